// Round 1
// baseline (4949.152 us; speedup 1.0000x reference)
//
#include <hip/hip_runtime.h>
#include <math.h>

#define NEG_SLOPE 0.2f
#define BM 64
#define BN 64
#define BK 16

// ---- float atomic-max encoding (order-preserving uint mapping) ----
__device__ __forceinline__ unsigned int enc_f(float f) {
    unsigned int u = __float_as_uint(f);
    return (u & 0x80000000u) ? ~u : (u | 0x80000000u);
}
__device__ __forceinline__ float dec_f(unsigned int u) {
    return __uint_as_float((u & 0x80000000u) ? (u ^ 0x80000000u) : ~u);
}

// ---- fp32 tiled GEMM: C[M,Ncol] = A[M,K] * B[K,Ncol], Ncol multiple of 64, K multiple of 16 ----
__global__ __launch_bounds__(256) void gemm_kernel(const float* __restrict__ A,
                                                   const float* __restrict__ B,
                                                   float* __restrict__ C,
                                                   int M, int K, int Ncol) {
    __shared__ float As[BK][BM + 4];
    __shared__ float Bs[BK][BN];
    const int tid = threadIdx.x;
    const int tx = tid & 15, ty = tid >> 4;
    const int row0 = blockIdx.y * BM, col0 = blockIdx.x * BN;

    float acc[4][4] = {};

    const int la_r = tid >> 2;          // 0..63 row in tile
    const int la_k = (tid & 3) * 4;     // 0,4,8,12
    const int lb_k = tid >> 4;          // 0..15
    const int lb_n = (tid & 15) * 4;    // 0..60

    for (int k0 = 0; k0 < K; k0 += BK) {
        float4 av = make_float4(0.f, 0.f, 0.f, 0.f);
        int ar = row0 + la_r;
        if (ar < M) av = *(const float4*)(A + (size_t)ar * K + k0 + la_k);
        As[la_k + 0][la_r] = av.x;
        As[la_k + 1][la_r] = av.y;
        As[la_k + 2][la_r] = av.z;
        As[la_k + 3][la_r] = av.w;

        float4 bv = *(const float4*)(B + (size_t)(k0 + lb_k) * Ncol + col0 + lb_n);
        *(float4*)&Bs[lb_k][lb_n] = bv;
        __syncthreads();

#pragma unroll
        for (int kk = 0; kk < BK; ++kk) {
            float4 a4 = *(const float4*)&As[kk][ty * 4];
            float4 b4 = *(const float4*)&Bs[kk][tx * 4];
            float a[4] = {a4.x, a4.y, a4.z, a4.w};
            float b[4] = {b4.x, b4.y, b4.z, b4.w};
#pragma unroll
            for (int i = 0; i < 4; ++i)
#pragma unroll
                for (int j = 0; j < 4; ++j) acc[i][j] += a[i] * b[j];
        }
        __syncthreads();
    }
#pragma unroll
    for (int i = 0; i < 4; ++i) {
        int row = row0 + ty * 4 + i;
        if (row < M) {
            float4 v = make_float4(acc[i][0], acc[i][1], acc[i][2], acc[i][3]);
            *(float4*)(C + (size_t)row * Ncol + col0 + tx * 4) = v;
        }
    }
}

// ---- per-node alpha_src/alpha_dst: wave per (node, head) ----
__global__ __launch_bounds__(256) void node_alpha_kernel(const float* __restrict__ xh,
                                                         const float* __restrict__ a_src,
                                                         const float* __restrict__ a_dst,
                                                         float* __restrict__ asrc,
                                                         float* __restrict__ adst, int N) {
    int n = blockIdx.x;
    int h = threadIdx.x >> 6;
    int c = threadIdx.x & 63;
    float v = xh[(size_t)n * 256 + h * 64 + c];
    float ps = v * a_src[h * 64 + c];
    float pd = v * a_dst[h * 64 + c];
#pragma unroll
    for (int off = 32; off > 0; off >>= 1) {
        ps += __shfl_down(ps, off);
        pd += __shfl_down(pd, off);
    }
    if (c == 0) {
        asrc[n * 4 + h] = ps;
        adst[n * 4 + h] = pd;
    }
}

// ---- ce[h] = sum_c W_e[0, h*64+c] * a_e[h, c]  (edge_attr outer-product collapse) ----
__global__ __launch_bounds__(256) void ce_kernel(const float* __restrict__ W_e,
                                                 const float* __restrict__ a_e,
                                                 float* __restrict__ ce) {
    int h = threadIdx.x >> 6;
    int c = threadIdx.x & 63;
    float p = W_e[h * 64 + c] * a_e[h * 64 + c];
#pragma unroll
    for (int off = 32; off > 0; off >>= 1) p += __shfl_down(p, off);
    if (c == 0) ce[h] = p;
}

// ---- init: h_out = bias broadcast, amax=enc(-lowest), denom=0 ----
__global__ __launch_bounds__(256) void init_kernel(float* __restrict__ hout,
                                                   const float* __restrict__ b,
                                                   unsigned int* __restrict__ amax,
                                                   float* __restrict__ denom, int N) {
    int i = blockIdx.x * blockDim.x + threadIdx.x;
    if (i < N * 256) hout[i] = b[i & 255];
    if (i < N * 4) {
        amax[i] = 0u;   // encoded value below every real float
        denom[i] = 0.f;
    }
}

// ---- pass1: alpha_raw = leakyrelu(asrc[src]+adst[dst]+ea*ce); atomicMax into amax[dst] ----
__global__ __launch_bounds__(256) void edge_pass1(const int* __restrict__ src,
                                                  const int* __restrict__ dst,
                                                  const float* __restrict__ edge_attr,
                                                  const float* __restrict__ asrc,
                                                  const float* __restrict__ adst,
                                                  const float* __restrict__ ce,
                                                  float* __restrict__ alpha,
                                                  unsigned int* __restrict__ amax, int E) {
    int e = blockIdx.x * blockDim.x + threadIdx.x;
    if (e >= E) return;
    int s = src[e], d = dst[e];
    float ea = edge_attr[e];
    float4 as4 = *(const float4*)(asrc + (size_t)s * 4);
    float4 ad4 = *(const float4*)(adst + (size_t)d * 4);
    float4 c4 = *(const float4*)ce;
    float a0 = as4.x + ad4.x + ea * c4.x;
    float a1 = as4.y + ad4.y + ea * c4.y;
    float a2 = as4.z + ad4.z + ea * c4.z;
    float a3 = as4.w + ad4.w + ea * c4.w;
    a0 = a0 > 0.f ? a0 : NEG_SLOPE * a0;
    a1 = a1 > 0.f ? a1 : NEG_SLOPE * a1;
    a2 = a2 > 0.f ? a2 : NEG_SLOPE * a2;
    a3 = a3 > 0.f ? a3 : NEG_SLOPE * a3;
    *(float4*)(alpha + (size_t)e * 4) = make_float4(a0, a1, a2, a3);
    atomicMax(amax + (size_t)d * 4 + 0, enc_f(a0));
    atomicMax(amax + (size_t)d * 4 + 1, enc_f(a1));
    atomicMax(amax + (size_t)d * 4 + 2, enc_f(a2));
    atomicMax(amax + (size_t)d * 4 + 3, enc_f(a3));
}

// ---- pass2: alpha = exp(alpha - amax[dst]); atomicAdd denom[dst] ----
__global__ __launch_bounds__(256) void edge_pass2(const int* __restrict__ dst,
                                                  float* __restrict__ alpha,
                                                  const unsigned int* __restrict__ amax,
                                                  float* __restrict__ denom, int E) {
    int e = blockIdx.x * blockDim.x + threadIdx.x;
    if (e >= E) return;
    int d = dst[e];
    float4 al = *(const float4*)(alpha + (size_t)e * 4);
    const unsigned int* mp = amax + (size_t)d * 4;
    float e0 = expf(al.x - dec_f(mp[0]));
    float e1 = expf(al.y - dec_f(mp[1]));
    float e2 = expf(al.z - dec_f(mp[2]));
    float e3 = expf(al.w - dec_f(mp[3]));
    *(float4*)(alpha + (size_t)e * 4) = make_float4(e0, e1, e2, e3);
    float* dp = denom + (size_t)d * 4;
    unsafeAtomicAdd(dp + 0, e0);
    unsafeAtomicAdd(dp + 1, e1);
    unsafeAtomicAdd(dp + 2, e2);
    unsafeAtomicAdd(dp + 3, e3);
}

// ---- pass3: one wave per edge; normalize alpha, write w, scatter msg into h_out ----
__global__ __launch_bounds__(256) void edge_pass3(const int* __restrict__ src,
                                                  const int* __restrict__ dst,
                                                  const float* __restrict__ edge_atten,
                                                  const float* __restrict__ xh,
                                                  const float* __restrict__ denom,
                                                  float* __restrict__ alpha,
                                                  float* __restrict__ hout, int E) {
    int e = blockIdx.x * 4 + (threadIdx.x >> 6);
    if (e >= E) return;
    int lane = threadIdx.x & 63;
    int s = src[e], d = dst[e];
    int h = lane >> 4;
    float4 ex4 = *(const float4*)(alpha + (size_t)e * 4);
    float4 dn4 = *(const float4*)(denom + (size_t)d * 4);
    float att = edge_atten[e];
    float exv = ((const float*)&ex4)[h];
    float dnv = ((const float*)&dn4)[h];
    float aln = exv / (dnv + 1e-16f);
    if ((lane & 15) == 0) alpha[(size_t)e * 4 + h] = aln;  // normalized alpha -> output w
    float sc = aln * att;
    float4 xv = *(const float4*)(xh + (size_t)s * 256 + lane * 4);
    float* hp = hout + (size_t)d * 256 + lane * 4;
    unsafeAtomicAdd(hp + 0, xv.x * sc);
    unsafeAtomicAdd(hp + 1, xv.y * sc);
    unsafeAtomicAdd(hp + 2, xv.z * sc);
    unsafeAtomicAdd(hp + 3, xv.w * sc);
}

extern "C" void kernel_launch(void* const* d_in, const int* in_sizes, int n_in,
                              void* d_out, int out_size, void* d_ws, size_t ws_size,
                              hipStream_t stream) {
    const float* x          = (const float*)d_in[0];
    const int*   ei         = (const int*)d_in[1];
    // d_in[2] = batch (unused)
    const float* edge_attr  = (const float*)d_in[3];
    const float* edge_atten = (const float*)d_in[4];
    const float* W1     = (const float*)d_in[5];
    const float* a_src1 = (const float*)d_in[6];
    const float* a_dst1 = (const float*)d_in[7];
    const float* W_e1   = (const float*)d_in[8];
    const float* a_e1   = (const float*)d_in[9];
    const float* b1     = (const float*)d_in[10];
    const float* W2     = (const float*)d_in[11];
    const float* a_src2 = (const float*)d_in[12];
    const float* a_dst2 = (const float*)d_in[13];
    const float* W_e2   = (const float*)d_in[14];
    const float* a_e2   = (const float*)d_in[15];
    const float* b2     = (const float*)d_in[16];

    const int N = in_sizes[0] / 128;   // 20000
    const int E = in_sizes[1] / 2;     // 640000
    const int* srcp = ei;
    const int* dstp = ei + E;

    float* ws = (float*)d_ws;
    float* xh   = ws;                                  // N*256
    float* h1   = xh + (size_t)N * 256;                // N*256
    float* asrc = h1 + (size_t)N * 256;                // N*4
    float* adst = asrc + (size_t)N * 4;                // N*4
    unsigned int* amax = (unsigned int*)(adst + (size_t)N * 4);  // N*4
    float* denom = (float*)amax + (size_t)N * 4;       // N*4
    float* ce    = denom + (size_t)N * 4;              // 4

    float* hout2 = (float*)d_out;                      // N*256 (final h)
    float* w1    = hout2 + (size_t)N * 256;            // E*4
    float* w2    = w1 + (size_t)E * 4;                 // E*4

    dim3 gemm_grid(256 / BN, (N + BM - 1) / BM);
    int eb = (E + 255) / 256;
    int ib = (N * 256 + 255) / 256;

    // ---------------- layer 1 ----------------
    gemm_kernel<<<gemm_grid, 256, 0, stream>>>(x, W1, xh, N, 128, 256);
    node_alpha_kernel<<<N, 256, 0, stream>>>(xh, a_src1, a_dst1, asrc, adst, N);
    ce_kernel<<<1, 256, 0, stream>>>(W_e1, a_e1, ce);
    init_kernel<<<ib, 256, 0, stream>>>(h1, b1, amax, denom, N);
    edge_pass1<<<eb, 256, 0, stream>>>(srcp, dstp, edge_attr, asrc, adst, ce, w1, amax, E);
    edge_pass2<<<eb, 256, 0, stream>>>(dstp, w1, amax, denom, E);
    edge_pass3<<<(E + 3) / 4, 256, 0, stream>>>(srcp, dstp, edge_atten, xh, denom, w1, h1, E);

    // ---------------- layer 2 ----------------
    gemm_kernel<<<gemm_grid, 256, 0, stream>>>(h1, W2, xh, N, 256, 256);
    node_alpha_kernel<<<N, 256, 0, stream>>>(xh, a_src2, a_dst2, asrc, adst, N);
    ce_kernel<<<1, 256, 0, stream>>>(W_e2, a_e2, ce);
    init_kernel<<<ib, 256, 0, stream>>>(hout2, b2, amax, denom, N);
    edge_pass1<<<eb, 256, 0, stream>>>(srcp, dstp, edge_attr, asrc, adst, ce, w2, amax, E);
    edge_pass2<<<eb, 256, 0, stream>>>(dstp, w2, amax, denom, E);
    edge_pass3<<<(E + 3) / 4, 256, 0, stream>>>(srcp, dstp, edge_atten, xh, denom, w2, hout2, E);
}

// Round 2
// 1060.505 us; speedup vs baseline: 4.6668x; 4.6668x over previous
//
#include <hip/hip_runtime.h>
#include <math.h>

#define NEG_SLOPE 0.2f
#define BM 64
#define BN 64
#define BK 16

// ---- float atomic-max encoding (order-preserving uint mapping) ----
__device__ __forceinline__ unsigned int enc_f(float f) {
    unsigned int u = __float_as_uint(f);
    return (u & 0x80000000u) ? ~u : (u | 0x80000000u);
}
__device__ __forceinline__ float dec_f(unsigned int u) {
    return __uint_as_float((u & 0x80000000u) ? (u ^ 0x80000000u) : ~u);
}

// ---- fp32 tiled GEMM: C[M,Ncol] = A[M,K] * B[K,Ncol] ----
__global__ __launch_bounds__(256) void gemm_kernel(const float* __restrict__ A,
                                                   const float* __restrict__ B,
                                                   float* __restrict__ C,
                                                   int M, int K, int Ncol) {
    __shared__ float As[BK][BM + 4];
    __shared__ float Bs[BK][BN];
    const int tid = threadIdx.x;
    const int tx = tid & 15, ty = tid >> 4;
    const int row0 = blockIdx.y * BM, col0 = blockIdx.x * BN;

    float acc[4][4] = {};

    const int la_r = tid >> 2;
    const int la_k = (tid & 3) * 4;
    const int lb_k = tid >> 4;
    const int lb_n = (tid & 15) * 4;

    for (int k0 = 0; k0 < K; k0 += BK) {
        float4 av = make_float4(0.f, 0.f, 0.f, 0.f);
        int ar = row0 + la_r;
        if (ar < M) av = *(const float4*)(A + (size_t)ar * K + k0 + la_k);
        As[la_k + 0][la_r] = av.x;
        As[la_k + 1][la_r] = av.y;
        As[la_k + 2][la_r] = av.z;
        As[la_k + 3][la_r] = av.w;

        float4 bv = *(const float4*)(B + (size_t)(k0 + lb_k) * Ncol + col0 + lb_n);
        *(float4*)&Bs[lb_k][lb_n] = bv;
        __syncthreads();

#pragma unroll
        for (int kk = 0; kk < BK; ++kk) {
            float4 a4 = *(const float4*)&As[kk][ty * 4];
            float4 b4 = *(const float4*)&Bs[kk][tx * 4];
            float a[4] = {a4.x, a4.y, a4.z, a4.w};
            float b[4] = {b4.x, b4.y, b4.z, b4.w};
#pragma unroll
            for (int i = 0; i < 4; ++i)
#pragma unroll
                for (int j = 0; j < 4; ++j) acc[i][j] += a[i] * b[j];
        }
        __syncthreads();
    }
#pragma unroll
    for (int i = 0; i < 4; ++i) {
        int row = row0 + ty * 4 + i;
        if (row < M) {
            float4 v = make_float4(acc[i][0], acc[i][1], acc[i][2], acc[i][3]);
            *(float4*)(C + (size_t)row * Ncol + col0 + tx * 4) = v;
        }
    }
}

// ---- per-node alpha_src/alpha_dst ----
__global__ __launch_bounds__(256) void node_alpha_kernel(const float* __restrict__ xh,
                                                         const float* __restrict__ a_src,
                                                         const float* __restrict__ a_dst,
                                                         float* __restrict__ asrc,
                                                         float* __restrict__ adst, int N) {
    int n = blockIdx.x;
    int h = threadIdx.x >> 6;
    int c = threadIdx.x & 63;
    float v = xh[(size_t)n * 256 + h * 64 + c];
    float ps = v * a_src[h * 64 + c];
    float pd = v * a_dst[h * 64 + c];
#pragma unroll
    for (int off = 32; off > 0; off >>= 1) {
        ps += __shfl_down(ps, off);
        pd += __shfl_down(pd, off);
    }
    if (c == 0) {
        asrc[n * 4 + h] = ps;
        adst[n * 4 + h] = pd;
    }
}

// ---- ce[h] = sum_c W_e[0, h*64+c] * a_e[h, c] ----
__global__ __launch_bounds__(256) void ce_kernel(const float* __restrict__ W_e,
                                                 const float* __restrict__ a_e,
                                                 float* __restrict__ ce) {
    int h = threadIdx.x >> 6;
    int c = threadIdx.x & 63;
    float p = W_e[h * 64 + c] * a_e[h * 64 + c];
#pragma unroll
    for (int off = 32; off > 0; off >>= 1) p += __shfl_down(p, off);
    if (c == 0) ce[h] = p;
}

// ---- init amax/denom only (hout no longer needs init: gather writes it fully) ----
__global__ __launch_bounds__(256) void init_kernel(unsigned int* __restrict__ amax,
                                                   float* __restrict__ denom, int N4) {
    int i = blockIdx.x * blockDim.x + threadIdx.x;
    if (i < N4) {
        amax[i] = 0u;
        denom[i] = 0.f;
    }
}

// ==================== CSR build ====================
__global__ __launch_bounds__(256) void zero_deg(int* __restrict__ deg, int N) {
    int i = blockIdx.x * blockDim.x + threadIdx.x;
    if (i < N) deg[i] = 0;
}

__global__ __launch_bounds__(256) void hist_kernel(const int* __restrict__ dst,
                                                   int* __restrict__ deg, int E) {
    int e = blockIdx.x * blockDim.x + threadIdx.x;
    if (e < E) atomicAdd(&deg[dst[e]], 1);
}

// single-block exclusive scan over deg -> off[0..N], cursor copy
__global__ __launch_bounds__(1024) void scan_kernel(const int* __restrict__ deg,
                                                    int* __restrict__ off,
                                                    int* __restrict__ cursor, int N) {
    __shared__ int buf[1024];
    __shared__ int s_carry;
    if (threadIdx.x == 0) s_carry = 0;
    __syncthreads();
    for (int base = 0; base < N; base += 1024) {
        int i = base + (int)threadIdx.x;
        int v = (i < N) ? deg[i] : 0;
        buf[threadIdx.x] = v;
        __syncthreads();
        for (int ofs = 1; ofs < 1024; ofs <<= 1) {
            int t = (threadIdx.x >= (unsigned)ofs) ? buf[threadIdx.x - ofs] : 0;
            __syncthreads();
            buf[threadIdx.x] += t;
            __syncthreads();
        }
        int carry = s_carry;
        int excl = carry + buf[threadIdx.x] - v;
        if (i < N) { off[i] = excl; cursor[i] = excl; }
        __syncthreads();
        if (threadIdx.x == 0) s_carry = carry + buf[1023];
        __syncthreads();
    }
    if (threadIdx.x == 0) off[N] = s_carry;
}

__global__ __launch_bounds__(256) void fill_kernel(const int* __restrict__ dst,
                                                   int* __restrict__ cursor,
                                                   int* __restrict__ perm, int E) {
    int e = blockIdx.x * blockDim.x + threadIdx.x;
    if (e < E) {
        int pos = atomicAdd(&cursor[dst[e]], 1);
        perm[pos] = e;
    }
}

// ==================== edge softmax ====================
__global__ __launch_bounds__(256) void edge_pass1(const int* __restrict__ src,
                                                  const int* __restrict__ dst,
                                                  const float* __restrict__ edge_attr,
                                                  const float* __restrict__ asrc,
                                                  const float* __restrict__ adst,
                                                  const float* __restrict__ ce,
                                                  float* __restrict__ alpha,
                                                  unsigned int* __restrict__ amax, int E) {
    int e = blockIdx.x * blockDim.x + threadIdx.x;
    if (e >= E) return;
    int s = src[e], d = dst[e];
    float ea = edge_attr[e];
    float4 as4 = *(const float4*)(asrc + (size_t)s * 4);
    float4 ad4 = *(const float4*)(adst + (size_t)d * 4);
    float4 c4 = *(const float4*)ce;
    float a0 = as4.x + ad4.x + ea * c4.x;
    float a1 = as4.y + ad4.y + ea * c4.y;
    float a2 = as4.z + ad4.z + ea * c4.z;
    float a3 = as4.w + ad4.w + ea * c4.w;
    a0 = a0 > 0.f ? a0 : NEG_SLOPE * a0;
    a1 = a1 > 0.f ? a1 : NEG_SLOPE * a1;
    a2 = a2 > 0.f ? a2 : NEG_SLOPE * a2;
    a3 = a3 > 0.f ? a3 : NEG_SLOPE * a3;
    *(float4*)(alpha + (size_t)e * 4) = make_float4(a0, a1, a2, a3);
    atomicMax(amax + (size_t)d * 4 + 0, enc_f(a0));
    atomicMax(amax + (size_t)d * 4 + 1, enc_f(a1));
    atomicMax(amax + (size_t)d * 4 + 2, enc_f(a2));
    atomicMax(amax + (size_t)d * 4 + 3, enc_f(a3));
}

__global__ __launch_bounds__(256) void edge_pass2(const int* __restrict__ dst,
                                                  float* __restrict__ alpha,
                                                  const unsigned int* __restrict__ amax,
                                                  float* __restrict__ denom, int E) {
    int e = blockIdx.x * blockDim.x + threadIdx.x;
    if (e >= E) return;
    int d = dst[e];
    float4 al = *(const float4*)(alpha + (size_t)e * 4);
    const unsigned int* mp = amax + (size_t)d * 4;
    float e0 = expf(al.x - dec_f(mp[0]));
    float e1 = expf(al.y - dec_f(mp[1]));
    float e2 = expf(al.z - dec_f(mp[2]));
    float e3 = expf(al.w - dec_f(mp[3]));
    *(float4*)(alpha + (size_t)e * 4) = make_float4(e0, e1, e2, e3);
    float* dp = denom + (size_t)d * 4;
    unsafeAtomicAdd(dp + 0, e0);
    unsafeAtomicAdd(dp + 1, e1);
    unsafeAtomicAdd(dp + 2, e2);
    unsafeAtomicAdd(dp + 3, e3);
}

// ---- normalize: w[e] = exp / (denom[dst]+eps), coalesced in-place ----
__global__ __launch_bounds__(256) void normalize_w(const int* __restrict__ dst,
                                                   const float* __restrict__ denom,
                                                   float* __restrict__ w, int E) {
    int e = blockIdx.x * blockDim.x + threadIdx.x;
    if (e >= E) return;
    int d = dst[e];
    float4 dn = *(const float4*)(denom + (size_t)d * 4);
    float4 v = *(const float4*)(w + (size_t)e * 4);
    v.x = v.x / (dn.x + 1e-16f);
    v.y = v.y / (dn.y + 1e-16f);
    v.z = v.z / (dn.z + 1e-16f);
    v.w = v.w / (dn.w + 1e-16f);
    *(float4*)(w + (size_t)e * 4) = v;
}

// ---- CSR gather-aggregate: one wave per node, acc in registers, no atomics ----
__global__ __launch_bounds__(256) void gather_agg(const int* __restrict__ perm,
                                                  const int* __restrict__ off,
                                                  const int* __restrict__ src,
                                                  const float* __restrict__ edge_atten,
                                                  const float* __restrict__ w,
                                                  const float* __restrict__ xh,
                                                  const float* __restrict__ bias,
                                                  float* __restrict__ hout, int N) {
    int n = blockIdx.x * 4 + (threadIdx.x >> 6);
    if (n >= N) return;
    int lane = threadIdx.x & 63;
    int h = lane >> 4;
    int o0 = off[n], o1 = off[n + 1];
    float4 acc = *(const float4*)(bias + lane * 4);

    int e = (o0 < o1) ? perm[o0] : 0;
    for (int k = o0; k < o1; ++k) {
        int s = src[e];
        float aln = w[(size_t)e * 4 + h];
        float att = edge_atten[e];
        int e_next = (k + 1 < o1) ? perm[k + 1] : 0;
        float sc = aln * att;
        const float4 xv = *(const float4*)(xh + (size_t)s * 256 + lane * 4);
        acc.x += xv.x * sc;
        acc.y += xv.y * sc;
        acc.z += xv.z * sc;
        acc.w += xv.w * sc;
        e = e_next;
    }
    *(float4*)(hout + (size_t)n * 256 + lane * 4) = acc;
}

extern "C" void kernel_launch(void* const* d_in, const int* in_sizes, int n_in,
                              void* d_out, int out_size, void* d_ws, size_t ws_size,
                              hipStream_t stream) {
    const float* x          = (const float*)d_in[0];
    const int*   ei         = (const int*)d_in[1];
    const float* edge_attr  = (const float*)d_in[3];
    const float* edge_atten = (const float*)d_in[4];
    const float* W1     = (const float*)d_in[5];
    const float* a_src1 = (const float*)d_in[6];
    const float* a_dst1 = (const float*)d_in[7];
    const float* W_e1   = (const float*)d_in[8];
    const float* a_e1   = (const float*)d_in[9];
    const float* b1     = (const float*)d_in[10];
    const float* W2     = (const float*)d_in[11];
    const float* a_src2 = (const float*)d_in[12];
    const float* a_dst2 = (const float*)d_in[13];
    const float* W_e2   = (const float*)d_in[14];
    const float* a_e2   = (const float*)d_in[15];
    const float* b2     = (const float*)d_in[16];

    const int N = in_sizes[0] / 128;   // 20000
    const int E = in_sizes[1] / 2;     // 640000
    const int* srcp = ei;
    const int* dstp = ei + E;

    float* ws = (float*)d_ws;
    float* xh   = ws;                                  // N*256
    float* h1   = xh + (size_t)N * 256;                // N*256
    float* asrc = h1 + (size_t)N * 256;                // N*4
    float* adst = asrc + (size_t)N * 4;                // N*4
    unsigned int* amax = (unsigned int*)(adst + (size_t)N * 4);  // N*4
    float* denom = (float*)amax + (size_t)N * 4;       // N*4
    float* ce    = denom + (size_t)N * 4;              // 4 (pad 4)
    int* deg     = (int*)(ce + 4);                     // N
    int* off     = deg + N;                            // N+1
    int* cursor  = off + N + 1;                        // N
    int* perm    = cursor + N;                         // E

    float* hout2 = (float*)d_out;                      // N*256
    float* w1    = hout2 + (size_t)N * 256;            // E*4
    float* w2    = w1 + (size_t)E * 4;                 // E*4

    dim3 gemm_grid(256 / BN, (N + BM - 1) / BM);
    int eb = (E + 255) / 256;
    int nb = (N + 255) / 256;
    int ib = (N * 4 + 255) / 256;
    int gb = (N + 3) / 4;

    // ---------------- CSR build (once; shared by both layers) ----------------
    zero_deg<<<nb, 256, 0, stream>>>(deg, N);
    hist_kernel<<<eb, 256, 0, stream>>>(dstp, deg, E);
    scan_kernel<<<1, 1024, 0, stream>>>(deg, off, cursor, N);
    fill_kernel<<<eb, 256, 0, stream>>>(dstp, cursor, perm, E);

    // ---------------- layer 1 ----------------
    gemm_kernel<<<gemm_grid, 256, 0, stream>>>(x, W1, xh, N, 128, 256);
    node_alpha_kernel<<<N, 256, 0, stream>>>(xh, a_src1, a_dst1, asrc, adst, N);
    ce_kernel<<<1, 256, 0, stream>>>(W_e1, a_e1, ce);
    init_kernel<<<ib, 256, 0, stream>>>(amax, denom, N * 4);
    edge_pass1<<<eb, 256, 0, stream>>>(srcp, dstp, edge_attr, asrc, adst, ce, w1, amax, E);
    edge_pass2<<<eb, 256, 0, stream>>>(dstp, w1, amax, denom, E);
    normalize_w<<<eb, 256, 0, stream>>>(dstp, denom, w1, E);
    gather_agg<<<gb, 256, 0, stream>>>(perm, off, srcp, edge_atten, w1, xh, b1, h1, N);

    // ---------------- layer 2 ----------------
    gemm_kernel<<<gemm_grid, 256, 0, stream>>>(h1, W2, xh, N, 256, 256);
    node_alpha_kernel<<<N, 256, 0, stream>>>(xh, a_src2, a_dst2, asrc, adst, N);
    ce_kernel<<<1, 256, 0, stream>>>(W_e2, a_e2, ce);
    init_kernel<<<ib, 256, 0, stream>>>(amax, denom, N * 4);
    edge_pass1<<<eb, 256, 0, stream>>>(srcp, dstp, edge_attr, asrc, adst, ce, w2, amax, E);
    edge_pass2<<<eb, 256, 0, stream>>>(dstp, w2, amax, denom, E);
    normalize_w<<<eb, 256, 0, stream>>>(dstp, denom, w2, E);
    gather_agg<<<gb, 256, 0, stream>>>(perm, off, srcp, edge_atten, w2, xh, b2, hout2, N);
}

// Round 3
// 549.201 us; speedup vs baseline: 9.0115x; 1.9310x over previous
//
#include <hip/hip_runtime.h>
#include <math.h>

#define NEG_SLOPE 0.2f
#define BM 64
#define BN 64
#define BK 16
#define CAP 256   // max in-edges per node held in LDS; global fallback beyond

// ---- fp32 tiled GEMM: C[M,Ncol] = A[M,K] * B[K,Ncol] ----
__global__ __launch_bounds__(256) void gemm_kernel(const float* __restrict__ A,
                                                   const float* __restrict__ B,
                                                   float* __restrict__ C,
                                                   int M, int K, int Ncol) {
    __shared__ float As[BK][BM + 4];
    __shared__ float Bs[BK][BN];
    const int tid = threadIdx.x;
    const int tx = tid & 15, ty = tid >> 4;
    const int row0 = blockIdx.y * BM, col0 = blockIdx.x * BN;

    float acc[4][4] = {};

    const int la_r = tid >> 2;
    const int la_k = (tid & 3) * 4;
    const int lb_k = tid >> 4;
    const int lb_n = (tid & 15) * 4;

    for (int k0 = 0; k0 < K; k0 += BK) {
        float4 av = make_float4(0.f, 0.f, 0.f, 0.f);
        int ar = row0 + la_r;
        if (ar < M) av = *(const float4*)(A + (size_t)ar * K + k0 + la_k);
        As[la_k + 0][la_r] = av.x;
        As[la_k + 1][la_r] = av.y;
        As[la_k + 2][la_r] = av.z;
        As[la_k + 3][la_r] = av.w;

        float4 bv = *(const float4*)(B + (size_t)(k0 + lb_k) * Ncol + col0 + lb_n);
        *(float4*)&Bs[lb_k][lb_n] = bv;
        __syncthreads();

#pragma unroll
        for (int kk = 0; kk < BK; ++kk) {
            float4 a4 = *(const float4*)&As[kk][ty * 4];
            float4 b4 = *(const float4*)&Bs[kk][tx * 4];
            float a[4] = {a4.x, a4.y, a4.z, a4.w};
            float b[4] = {b4.x, b4.y, b4.z, b4.w};
#pragma unroll
            for (int i = 0; i < 4; ++i)
#pragma unroll
                for (int j = 0; j < 4; ++j) acc[i][j] += a[i] * b[j];
        }
        __syncthreads();
    }
#pragma unroll
    for (int i = 0; i < 4; ++i) {
        int row = row0 + ty * 4 + i;
        if (row < M) {
            float4 v = make_float4(acc[i][0], acc[i][1], acc[i][2], acc[i][3]);
            *(float4*)(C + (size_t)row * Ncol + col0 + tx * 4) = v;
        }
    }
}

// ---- per-node alpha_src/alpha_dst ----
__global__ __launch_bounds__(256) void node_alpha_kernel(const float* __restrict__ xh,
                                                         const float* __restrict__ a_src,
                                                         const float* __restrict__ a_dst,
                                                         float* __restrict__ asrc,
                                                         float* __restrict__ adst, int N) {
    int n = blockIdx.x;
    int h = threadIdx.x >> 6;
    int c = threadIdx.x & 63;
    float v = xh[(size_t)n * 256 + h * 64 + c];
    float ps = v * a_src[h * 64 + c];
    float pd = v * a_dst[h * 64 + c];
#pragma unroll
    for (int off = 32; off > 0; off >>= 1) {
        ps += __shfl_down(ps, off);
        pd += __shfl_down(pd, off);
    }
    if (c == 0) {
        asrc[n * 4 + h] = ps;
        adst[n * 4 + h] = pd;
    }
}

// ---- ce[h] = sum_c W_e[0, h*64+c] * a_e[h, c] ----
__global__ __launch_bounds__(256) void ce_kernel(const float* __restrict__ W_e,
                                                 const float* __restrict__ a_e,
                                                 float* __restrict__ ce) {
    int h = threadIdx.x >> 6;
    int c = threadIdx.x & 63;
    float p = W_e[h * 64 + c] * a_e[h * 64 + c];
#pragma unroll
    for (int off = 32; off > 0; off >>= 1) p += __shfl_down(p, off);
    if (c == 0) ce[h] = p;
}

// ==================== CSR build ====================
__global__ __launch_bounds__(256) void zero_deg(int* __restrict__ deg, int N) {
    int i = blockIdx.x * blockDim.x + threadIdx.x;
    if (i < N) deg[i] = 0;
}

__global__ __launch_bounds__(256) void hist_kernel(const int* __restrict__ dst,
                                                   int* __restrict__ deg, int E) {
    int e = blockIdx.x * blockDim.x + threadIdx.x;
    if (e < E) atomicAdd(&deg[dst[e]], 1);
}

__global__ __launch_bounds__(1024) void scan_kernel(const int* __restrict__ deg,
                                                    int* __restrict__ off,
                                                    int* __restrict__ cursor, int N) {
    __shared__ int buf[1024];
    __shared__ int s_carry;
    if (threadIdx.x == 0) s_carry = 0;
    __syncthreads();
    for (int base = 0; base < N; base += 1024) {
        int i = base + (int)threadIdx.x;
        int v = (i < N) ? deg[i] : 0;
        buf[threadIdx.x] = v;
        __syncthreads();
        for (int ofs = 1; ofs < 1024; ofs <<= 1) {
            int t = (threadIdx.x >= (unsigned)ofs) ? buf[threadIdx.x - ofs] : 0;
            __syncthreads();
            buf[threadIdx.x] += t;
            __syncthreads();
        }
        int carry = s_carry;
        int excl = carry + buf[threadIdx.x] - v;
        if (i < N) { off[i] = excl; cursor[i] = excl; }
        __syncthreads();
        if (threadIdx.x == 0) s_carry = carry + buf[1023];
        __syncthreads();
    }
    if (threadIdx.x == 0) off[N] = s_carry;
}

__global__ __launch_bounds__(256) void fill_kernel(const int* __restrict__ dst,
                                                   int* __restrict__ cursor,
                                                   int* __restrict__ perm, int E) {
    int e = blockIdx.x * blockDim.x + threadIdx.x;
    if (e < E) {
        int pos = atomicAdd(&cursor[dst[e]], 1);
        perm[pos] = e;
    }
}

// ==================== fused per-node softmax + aggregation (no atomics) ====================
// One wave per node. Phases 1-3 use lane=(edge_in_chunk*4 + head); phase 4 uses lane=channel.
__global__ __launch_bounds__(256) void node_fused(const int* __restrict__ perm,
                                                  const int* __restrict__ off,
                                                  const int* __restrict__ src,
                                                  const float* __restrict__ edge_attr,
                                                  const float* __restrict__ edge_atten,
                                                  const float* __restrict__ asrc,
                                                  const float* __restrict__ adst,
                                                  const float* __restrict__ ce,
                                                  const float* __restrict__ xh,
                                                  const float* __restrict__ bias,
                                                  float* __restrict__ w,
                                                  float* __restrict__ hout, int N) {
    __shared__ float exbuf[4][CAP * 4];
    const int wid = threadIdx.x >> 6;
    const int n = blockIdx.x * 4 + wid;
    if (n >= N) return;
    const int lane = threadIdx.x & 63;
    float* buf = exbuf[wid];
    const int o0 = off[n], o1 = off[n + 1];
    const int deg = o1 - o0;

    const int el = lane >> 2;      // 0..15: edge slot within chunk
    const int h = lane & 3;        // head
    const float adn = adst[(size_t)n * 4 + h];
    const float ceh = ce[h];

    // phase 1: raw alpha (leakyrelu), running per-head max
    float mh = -3.4e38f;
    for (int base = 0; base < deg; base += 16) {
        int idx = base + el;
        float a = -3.4e38f;
        if (idx < deg) {
            int e = perm[o0 + idx];
            int s = src[e];
            a = asrc[(size_t)s * 4 + h] + adn + edge_attr[e] * ceh;
            a = a > 0.f ? a : NEG_SLOPE * a;
            if (idx < CAP) buf[idx * 4 + h] = a;
            else w[(size_t)e * 4 + h] = a;
        }
        mh = fmaxf(mh, a);
    }
#pragma unroll
    for (int ofs = 4; ofs < 64; ofs <<= 1) mh = fmaxf(mh, __shfl_xor(mh, ofs));

    // phase 2: exp and per-head sum
    float sh = 0.f;
    for (int base = 0; base < deg; base += 16) {
        int idx = base + el;
        if (idx < deg) {
            float a;
            int e = -1;
            if (idx < CAP) a = buf[idx * 4 + h];
            else { e = perm[o0 + idx]; a = w[(size_t)e * 4 + h]; }
            float ex = __expf(a - mh);
            if (idx < CAP) buf[idx * 4 + h] = ex;
            else w[(size_t)e * 4 + h] = ex;
            sh += ex;
        }
    }
#pragma unroll
    for (int ofs = 4; ofs < 64; ofs <<= 1) sh += __shfl_xor(sh, ofs);
    const float rcp = 1.f / (sh + 1e-16f);

    // phase 3: normalize; write output w (16B per edge, 4 lanes each)
    for (int base = 0; base < deg; base += 16) {
        int idx = base + el;
        if (idx < deg) {
            int e = perm[o0 + idx];
            float ex = (idx < CAP) ? buf[idx * 4 + h] : w[(size_t)e * 4 + h];
            float aln = ex * rcp;
            w[(size_t)e * 4 + h] = aln;
            if (idx < CAP) buf[idx * 4 + h] = aln;
        }
    }

    // phase 4: aggregation, lane = channel
    const int hh = lane >> 4;
    float4 acc = *(const float4*)(bias + lane * 4);
    for (int k = 0; k < deg; ++k) {
        int e = perm[o0 + k];
        int s = src[e];
        float aln = (k < CAP) ? buf[k * 4 + hh] : w[(size_t)e * 4 + hh];
        float sc = aln * edge_atten[e];
        float4 xv = *(const float4*)(xh + (size_t)s * 256 + lane * 4);
        acc.x += xv.x * sc;
        acc.y += xv.y * sc;
        acc.z += xv.z * sc;
        acc.w += xv.w * sc;
    }
    *(float4*)(hout + (size_t)n * 256 + lane * 4) = acc;
}

extern "C" void kernel_launch(void* const* d_in, const int* in_sizes, int n_in,
                              void* d_out, int out_size, void* d_ws, size_t ws_size,
                              hipStream_t stream) {
    const float* x          = (const float*)d_in[0];
    const int*   ei         = (const int*)d_in[1];
    const float* edge_attr  = (const float*)d_in[3];
    const float* edge_atten = (const float*)d_in[4];
    const float* W1     = (const float*)d_in[5];
    const float* a_src1 = (const float*)d_in[6];
    const float* a_dst1 = (const float*)d_in[7];
    const float* W_e1   = (const float*)d_in[8];
    const float* a_e1   = (const float*)d_in[9];
    const float* b1     = (const float*)d_in[10];
    const float* W2     = (const float*)d_in[11];
    const float* a_src2 = (const float*)d_in[12];
    const float* a_dst2 = (const float*)d_in[13];
    const float* W_e2   = (const float*)d_in[14];
    const float* a_e2   = (const float*)d_in[15];
    const float* b2     = (const float*)d_in[16];

    const int N = in_sizes[0] / 128;   // 20000
    const int E = in_sizes[1] / 2;     // 640000
    const int* srcp = ei;
    const int* dstp = ei + E;

    float* ws = (float*)d_ws;
    float* xh   = ws;                                  // N*256
    float* h1   = xh + (size_t)N * 256;                // N*256
    float* asrc = h1 + (size_t)N * 256;                // N*4
    float* adst = asrc + (size_t)N * 4;                // N*4
    float* ce   = adst + (size_t)N * 4;                // 4 (pad 4)
    int* deg    = (int*)(ce + 4);                      // N
    int* off    = deg + N;                             // N+1
    int* cursor = off + N + 1;                         // N
    int* perm   = cursor + N;                          // E

    float* hout2 = (float*)d_out;                      // N*256
    float* w1    = hout2 + (size_t)N * 256;            // E*4
    float* w2    = w1 + (size_t)E * 4;                 // E*4

    dim3 gemm_grid(256 / BN, (N + BM - 1) / BM);
    int eb = (E + 255) / 256;
    int nb = (N + 255) / 256;
    int gb = (N + 3) / 4;

    // ---------------- CSR build (once; shared by both layers) ----------------
    zero_deg<<<nb, 256, 0, stream>>>(deg, N);
    hist_kernel<<<eb, 256, 0, stream>>>(dstp, deg, E);
    scan_kernel<<<1, 1024, 0, stream>>>(deg, off, cursor, N);
    fill_kernel<<<eb, 256, 0, stream>>>(dstp, cursor, perm, E);

    // ---------------- layer 1 ----------------
    gemm_kernel<<<gemm_grid, 256, 0, stream>>>(x, W1, xh, N, 128, 256);
    node_alpha_kernel<<<N, 256, 0, stream>>>(xh, a_src1, a_dst1, asrc, adst, N);
    ce_kernel<<<1, 256, 0, stream>>>(W_e1, a_e1, ce);
    node_fused<<<gb, 256, 0, stream>>>(perm, off, srcp, edge_attr, edge_atten,
                                       asrc, adst, ce, xh, b1, w1, h1, N);

    // ---------------- layer 2 ----------------
    gemm_kernel<<<gemm_grid, 256, 0, stream>>>(h1, W2, xh, N, 256, 256);
    node_alpha_kernel<<<N, 256, 0, stream>>>(xh, a_src2, a_dst2, asrc, adst, N);
    ce_kernel<<<1, 256, 0, stream>>>(W_e2, a_e2, ce);
    node_fused<<<gb, 256, 0, stream>>>(perm, off, srcp, edge_attr, edge_atten,
                                       asrc, adst, ce, xh, b2, w2, hout2, N);
}

// Round 4
// 516.593 us; speedup vs baseline: 9.5804x; 1.0631x over previous
//
#include <hip/hip_runtime.h>
#include <math.h>

#define NEG_SLOPE 0.2f
#define BM 128
#define BN 64
#define BK 16
#define CAP 128   // max in-edges per node held in LDS; global fallback beyond (deg~Binom(640K,1/20K), mean 32 — CAP=128 is 16+ sigma)

// ---- fp32 tiled GEMM: C[M,Ncol] = A[M,K] * B[K,Ncol]; 128x64 tile, 8x4 acc/thread ----
__global__ __launch_bounds__(256) void gemm_kernel(const float* __restrict__ A,
                                                   const float* __restrict__ B,
                                                   float* __restrict__ C,
                                                   int M, int K, int Ncol) {
    __shared__ float As[BK][BM + 4];
    __shared__ float Bs[BK][BN];
    const int tid = threadIdx.x;
    const int tx = tid & 15, ty = tid >> 4;
    const int row0 = blockIdx.y * BM, col0 = blockIdx.x * BN;

    float acc[8][4] = {};

    const int la_r = tid >> 2;          // 0..63
    const int la_k = (tid & 3) * 4;     // 0,4,8,12
    const int lb_k = tid >> 4;          // 0..15
    const int lb_n = (tid & 15) * 4;

    for (int k0 = 0; k0 < K; k0 += BK) {
#pragma unroll
        for (int half = 0; half < 2; ++half) {
            int r = la_r + half * 64;
            int ar = row0 + r;
            float4 av = make_float4(0.f, 0.f, 0.f, 0.f);
            if (ar < M) av = *(const float4*)(A + (size_t)ar * K + k0 + la_k);
            As[la_k + 0][r] = av.x;
            As[la_k + 1][r] = av.y;
            As[la_k + 2][r] = av.z;
            As[la_k + 3][r] = av.w;
        }
        float4 bv = *(const float4*)(B + (size_t)(k0 + lb_k) * Ncol + col0 + lb_n);
        *(float4*)&Bs[lb_k][lb_n] = bv;
        __syncthreads();

#pragma unroll
        for (int kk = 0; kk < BK; ++kk) {
            float4 a0 = *(const float4*)&As[kk][ty * 8];
            float4 a1 = *(const float4*)&As[kk][ty * 8 + 4];
            float4 b4 = *(const float4*)&Bs[kk][tx * 4];
            float a[8] = {a0.x, a0.y, a0.z, a0.w, a1.x, a1.y, a1.z, a1.w};
            float b[4] = {b4.x, b4.y, b4.z, b4.w};
#pragma unroll
            for (int i = 0; i < 8; ++i)
#pragma unroll
                for (int j = 0; j < 4; ++j) acc[i][j] += a[i] * b[j];
        }
        __syncthreads();
    }
#pragma unroll
    for (int i = 0; i < 8; ++i) {
        int row = row0 + ty * 8 + i;
        if (row < M) {
            float4 v = make_float4(acc[i][0], acc[i][1], acc[i][2], acc[i][3]);
            *(float4*)(C + (size_t)row * Ncol + col0 + tx * 4) = v;
        }
    }
}

// ---- per-node alpha_src/alpha_dst ----
__global__ __launch_bounds__(256) void node_alpha_kernel(const float* __restrict__ xh,
                                                         const float* __restrict__ a_src,
                                                         const float* __restrict__ a_dst,
                                                         float* __restrict__ asrc,
                                                         float* __restrict__ adst, int N) {
    int n = blockIdx.x;
    int h = threadIdx.x >> 6;
    int c = threadIdx.x & 63;
    float v = xh[(size_t)n * 256 + h * 64 + c];
    float ps = v * a_src[h * 64 + c];
    float pd = v * a_dst[h * 64 + c];
#pragma unroll
    for (int off = 32; off > 0; off >>= 1) {
        ps += __shfl_down(ps, off);
        pd += __shfl_down(pd, off);
    }
    if (c == 0) {
        asrc[n * 4 + h] = ps;
        adst[n * 4 + h] = pd;
    }
}

// ---- ce[h] = sum_c W_e[0, h*64+c] * a_e[h, c] ----
__global__ __launch_bounds__(256) void ce_kernel(const float* __restrict__ W_e,
                                                 const float* __restrict__ a_e,
                                                 float* __restrict__ ce) {
    int h = threadIdx.x >> 6;
    int c = threadIdx.x & 63;
    float p = W_e[h * 64 + c] * a_e[h * 64 + c];
#pragma unroll
    for (int off = 32; off > 0; off >>= 1) p += __shfl_down(p, off);
    if (c == 0) ce[h] = p;
}

// ==================== CSR build ====================
__global__ __launch_bounds__(256) void zero_deg(int* __restrict__ deg, int N) {
    int i = blockIdx.x * blockDim.x + threadIdx.x;
    if (i < N) deg[i] = 0;
}

__global__ __launch_bounds__(256) void hist_kernel(const int* __restrict__ dst,
                                                   int* __restrict__ deg, int E) {
    int e = blockIdx.x * blockDim.x + threadIdx.x;
    if (e < E) atomicAdd(&deg[dst[e]], 1);
}

// single-block exclusive scan, shuffle-based (2 barriers of work per 1024 chunk)
__global__ __launch_bounds__(1024) void scan_kernel(const int* __restrict__ deg,
                                                    int* __restrict__ off,
                                                    int* __restrict__ cursor, int N) {
    __shared__ int wsum[16];
    __shared__ int woff[16];
    __shared__ int s_carry, s_bt;
    if (threadIdx.x == 0) s_carry = 0;
    __syncthreads();
    const int lane = threadIdx.x & 63, wid = threadIdx.x >> 6;
    for (int base = 0; base < N; base += 1024) {
        int i = base + (int)threadIdx.x;
        int v = (i < N) ? deg[i] : 0;
        int incl = v;
#pragma unroll
        for (int ofs = 1; ofs < 64; ofs <<= 1) {
            int t = __shfl_up(incl, ofs);
            if (lane >= ofs) incl += t;
        }
        if (lane == 63) wsum[wid] = incl;
        __syncthreads();
        if (wid == 0) {
            int ws = (lane < 16) ? wsum[lane] : 0;
            int wincl = ws;
#pragma unroll
            for (int ofs = 1; ofs < 16; ofs <<= 1) {
                int t = __shfl_up(wincl, ofs);
                if (lane >= ofs) wincl += t;
            }
            if (lane < 16) woff[lane] = wincl - ws;
            if (lane == 15) s_bt = wincl;
        }
        __syncthreads();
        int excl = s_carry + woff[wid] + incl - v;
        if (i < N) { off[i] = excl; cursor[i] = excl; }
        __syncthreads();
        if (threadIdx.x == 0) s_carry += s_bt;
        __syncthreads();
    }
    if (threadIdx.x == 0) off[N] = s_carry;
}

__global__ __launch_bounds__(256) void fill_kernel(const int* __restrict__ dst,
                                                   int* __restrict__ cursor,
                                                   int* __restrict__ perm, int E) {
    int e = blockIdx.x * blockDim.x + threadIdx.x;
    if (e < E) {
        int pos = atomicAdd(&cursor[dst[e]], 1);
        perm[pos] = e;
    }
}

// ==================== fused per-node softmax + aggregation ====================
// One wave per node. Phases 1-3: lane = edge slot (all 4 heads in float4).
// Phase 4: lane = channel, unroll x4 for memory-level parallelism.
__global__ __launch_bounds__(256) void node_fused(const int* __restrict__ perm,
                                                  const int* __restrict__ off,
                                                  const int* __restrict__ src,
                                                  const float* __restrict__ edge_attr,
                                                  const float* __restrict__ edge_atten,
                                                  const float* __restrict__ asrc,
                                                  const float* __restrict__ adst,
                                                  const float* __restrict__ ce,
                                                  const float* __restrict__ xh,
                                                  const float* __restrict__ bias,
                                                  float* __restrict__ w,
                                                  float* __restrict__ hout, int N) {
    __shared__ float s_al[4][CAP * 4];
    __shared__ int s_src[4][CAP];
    const int wid = threadIdx.x >> 6;
    const int n = blockIdx.x * 4 + wid;
    if (n >= N) return;
    const int lane = threadIdx.x & 63;
    float* al = s_al[wid];
    int* sv = s_src[wid];
    const int o0 = off[n], o1 = off[n + 1];
    const int deg = o1 - o0;

    const float4 c4 = *(const float4*)ce;
    const float4 ad4 = *(const float4*)(adst + (size_t)n * 4);

    // phase 1: raw alpha (leakyrelu) per edge (all heads), running max
    float4 mx = make_float4(-3.4e38f, -3.4e38f, -3.4e38f, -3.4e38f);
    for (int idx = lane; idx < deg; idx += 64) {
        int e = perm[o0 + idx];
        int s = src[e];
        float ea = edge_attr[e];
        float4 as4 = *(const float4*)(asrc + (size_t)s * 4);
        float4 a;
        a.x = as4.x + ad4.x + ea * c4.x;
        a.y = as4.y + ad4.y + ea * c4.y;
        a.z = as4.z + ad4.z + ea * c4.z;
        a.w = as4.w + ad4.w + ea * c4.w;
        a.x = a.x > 0.f ? a.x : NEG_SLOPE * a.x;
        a.y = a.y > 0.f ? a.y : NEG_SLOPE * a.y;
        a.z = a.z > 0.f ? a.z : NEG_SLOPE * a.z;
        a.w = a.w > 0.f ? a.w : NEG_SLOPE * a.w;
        if (idx < CAP) {
            sv[idx] = s;
            *(float4*)&al[idx * 4] = a;
        } else {
            *(float4*)(w + (size_t)e * 4) = a;  // rare spill
        }
        mx.x = fmaxf(mx.x, a.x);
        mx.y = fmaxf(mx.y, a.y);
        mx.z = fmaxf(mx.z, a.z);
        mx.w = fmaxf(mx.w, a.w);
    }
#pragma unroll
    for (int ofs = 1; ofs < 64; ofs <<= 1) {
        mx.x = fmaxf(mx.x, __shfl_xor(mx.x, ofs));
        mx.y = fmaxf(mx.y, __shfl_xor(mx.y, ofs));
        mx.z = fmaxf(mx.z, __shfl_xor(mx.z, ofs));
        mx.w = fmaxf(mx.w, __shfl_xor(mx.w, ofs));
    }

    // phase 2: exp + sum
    float4 sm = make_float4(0.f, 0.f, 0.f, 0.f);
    for (int idx = lane; idx < deg; idx += 64) {
        float4 a;
        int e = -1;
        if (idx < CAP) a = *(const float4*)&al[idx * 4];
        else { e = perm[o0 + idx]; a = *(const float4*)(w + (size_t)e * 4); }
        a.x = __expf(a.x - mx.x);
        a.y = __expf(a.y - mx.y);
        a.z = __expf(a.z - mx.z);
        a.w = __expf(a.w - mx.w);
        if (idx < CAP) *(float4*)&al[idx * 4] = a;
        else *(float4*)(w + (size_t)e * 4) = a;
        sm.x += a.x; sm.y += a.y; sm.z += a.z; sm.w += a.w;
    }
#pragma unroll
    for (int ofs = 1; ofs < 64; ofs <<= 1) {
        sm.x += __shfl_xor(sm.x, ofs);
        sm.y += __shfl_xor(sm.y, ofs);
        sm.z += __shfl_xor(sm.z, ofs);
        sm.w += __shfl_xor(sm.w, ofs);
    }
    float4 rc;
    rc.x = 1.f / (sm.x + 1e-16f);
    rc.y = 1.f / (sm.y + 1e-16f);
    rc.z = 1.f / (sm.z + 1e-16f);
    rc.w = 1.f / (sm.w + 1e-16f);

    // phase 3: normalize, write w (float4/edge), fold edge_atten into LDS copy
    for (int idx = lane; idx < deg; idx += 64) {
        int e = perm[o0 + idx];
        float4 ex = (idx < CAP) ? *(const float4*)&al[idx * 4]
                                : *(const float4*)(w + (size_t)e * 4);
        float4 aln;
        aln.x = ex.x * rc.x;
        aln.y = ex.y * rc.y;
        aln.z = ex.z * rc.z;
        aln.w = ex.w * rc.w;
        *(float4*)(w + (size_t)e * 4) = aln;
        if (idx < CAP) {
            float att = edge_atten[e];
            aln.x *= att; aln.y *= att; aln.z *= att; aln.w *= att;
            *(float4*)&al[idx * 4] = aln;
        }
    }

    // phase 4: aggregation, lane = channel; unroll x4 for outstanding loads
    const int hh = lane >> 4;
    float4 acc = *(const float4*)(bias + lane * 4);
    const int kmax = deg < CAP ? deg : CAP;
    int k = 0;
    for (; k + 4 <= kmax; k += 4) {
        int s0 = sv[k], s1 = sv[k + 1], s2 = sv[k + 2], s3 = sv[k + 3];
        float c0 = al[(k + 0) * 4 + hh];
        float c1 = al[(k + 1) * 4 + hh];
        float c2 = al[(k + 2) * 4 + hh];
        float c3 = al[(k + 3) * 4 + hh];
        float4 x0 = *(const float4*)(xh + (size_t)s0 * 256 + lane * 4);
        float4 x1 = *(const float4*)(xh + (size_t)s1 * 256 + lane * 4);
        float4 x2 = *(const float4*)(xh + (size_t)s2 * 256 + lane * 4);
        float4 x3 = *(const float4*)(xh + (size_t)s3 * 256 + lane * 4);
        acc.x += x0.x * c0; acc.y += x0.y * c0; acc.z += x0.z * c0; acc.w += x0.w * c0;
        acc.x += x1.x * c1; acc.y += x1.y * c1; acc.z += x1.z * c1; acc.w += x1.w * c1;
        acc.x += x2.x * c2; acc.y += x2.y * c2; acc.z += x2.z * c2; acc.w += x2.w * c2;
        acc.x += x3.x * c3; acc.y += x3.y * c3; acc.z += x3.z * c3; acc.w += x3.w * c3;
    }
    for (; k < kmax; ++k) {
        int s = sv[k];
        float sc = al[k * 4 + hh];
        float4 xv = *(const float4*)(xh + (size_t)s * 256 + lane * 4);
        acc.x += xv.x * sc; acc.y += xv.y * sc; acc.z += xv.z * sc; acc.w += xv.w * sc;
    }
    for (k = CAP; k < deg; ++k) {   // rare spill path
        int e = perm[o0 + k];
        int s = src[e];
        float sc = w[(size_t)e * 4 + hh] * edge_atten[e];
        float4 xv = *(const float4*)(xh + (size_t)s * 256 + lane * 4);
        acc.x += xv.x * sc; acc.y += xv.y * sc; acc.z += xv.z * sc; acc.w += xv.w * sc;
    }
    *(float4*)(hout + (size_t)n * 256 + lane * 4) = acc;
}

extern "C" void kernel_launch(void* const* d_in, const int* in_sizes, int n_in,
                              void* d_out, int out_size, void* d_ws, size_t ws_size,
                              hipStream_t stream) {
    const float* x          = (const float*)d_in[0];
    const int*   ei         = (const int*)d_in[1];
    const float* edge_attr  = (const float*)d_in[3];
    const float* edge_atten = (const float*)d_in[4];
    const float* W1     = (const float*)d_in[5];
    const float* a_src1 = (const float*)d_in[6];
    const float* a_dst1 = (const float*)d_in[7];
    const float* W_e1   = (const float*)d_in[8];
    const float* a_e1   = (const float*)d_in[9];
    const float* b1     = (const float*)d_in[10];
    const float* W2     = (const float*)d_in[11];
    const float* a_src2 = (const float*)d_in[12];
    const float* a_dst2 = (const float*)d_in[13];
    const float* W_e2   = (const float*)d_in[14];
    const float* a_e2   = (const float*)d_in[15];
    const float* b2     = (const float*)d_in[16];

    const int N = in_sizes[0] / 128;   // 20000
    const int E = in_sizes[1] / 2;     // 640000
    const int* srcp = ei;
    const int* dstp = ei + E;

    float* ws = (float*)d_ws;
    float* xh   = ws;                                  // N*256
    float* h1   = xh + (size_t)N * 256;                // N*256
    float* asrc = h1 + (size_t)N * 256;                // N*4
    float* adst = asrc + (size_t)N * 4;                // N*4
    float* ce   = adst + (size_t)N * 4;                // 4 (pad 4)
    int* deg    = (int*)(ce + 4);                      // N
    int* off    = deg + N;                             // N+1
    int* cursor = off + N + 1;                         // N
    int* perm   = cursor + N;                          // E

    float* hout2 = (float*)d_out;                      // N*256
    float* w1    = hout2 + (size_t)N * 256;            // E*4
    float* w2    = w1 + (size_t)E * 4;                 // E*4

    dim3 gemm_grid(256 / BN, (N + BM - 1) / BM);
    int eb = (E + 255) / 256;
    int nb = (N + 255) / 256;
    int gb = (N + 3) / 4;

    // ---------------- CSR build (once; shared by both layers) ----------------
    zero_deg<<<nb, 256, 0, stream>>>(deg, N);
    hist_kernel<<<eb, 256, 0, stream>>>(dstp, deg, E);
    scan_kernel<<<1, 1024, 0, stream>>>(deg, off, cursor, N);
    fill_kernel<<<eb, 256, 0, stream>>>(dstp, cursor, perm, E);

    // ---------------- layer 1 ----------------
    gemm_kernel<<<gemm_grid, 256, 0, stream>>>(x, W1, xh, N, 128, 256);
    node_alpha_kernel<<<N, 256, 0, stream>>>(xh, a_src1, a_dst1, asrc, adst, N);
    ce_kernel<<<1, 256, 0, stream>>>(W_e1, a_e1, ce);
    node_fused<<<gb, 256, 0, stream>>>(perm, off, srcp, edge_attr, edge_atten,
                                       asrc, adst, ce, xh, b1, w1, h1, N);

    // ---------------- layer 2 ----------------
    gemm_kernel<<<gemm_grid, 256, 0, stream>>>(h1, W2, xh, N, 256, 256);
    node_alpha_kernel<<<N, 256, 0, stream>>>(xh, a_src2, a_dst2, asrc, adst, N);
    ce_kernel<<<1, 256, 0, stream>>>(W_e2, a_e2, ce);
    node_fused<<<gb, 256, 0, stream>>>(perm, off, srcp, edge_attr, edge_atten,
                                       asrc, adst, ce, xh, b2, w2, hout2, N);
}

// Round 5
// 453.225 us; speedup vs baseline: 10.9199x; 1.1398x over previous
//
#include <hip/hip_runtime.h>
#include <math.h>

#define NEG_SLOPE 0.2f
#define BM 128
#define BN 64
#define BK 16
#define CAP 128   // max in-edges/node in LDS; deg~Binom(640K,1/20K) mean 32, max~60 → ample

// bf16 helpers (RNE encode, shift decode)
__device__ __forceinline__ unsigned short f2bf(float f) {
    unsigned int u = __float_as_uint(f);
    return (unsigned short)((u + 0x7FFFu + ((u >> 16) & 1u)) >> 16);
}
__device__ __forceinline__ float bf2f(unsigned short s) {
    return __uint_as_float(((unsigned int)s) << 16);
}

// ---- fp32 tiled GEMM + bf16 shadow copy: C[M,Ncol]=A*B, C16 = bf16(C) ----
__global__ __launch_bounds__(256) void gemm_kernel(const float* __restrict__ A,
                                                   const float* __restrict__ B,
                                                   float* __restrict__ C,
                                                   unsigned short* __restrict__ C16,
                                                   int M, int K, int Ncol) {
    __shared__ float As[BK][BM + 4];
    __shared__ float Bs[BK][BN];
    const int tid = threadIdx.x;
    const int tx = tid & 15, ty = tid >> 4;
    const int row0 = blockIdx.y * BM, col0 = blockIdx.x * BN;

    float acc[8][4] = {};

    const int la_r = tid >> 2;
    const int la_k = (tid & 3) * 4;
    const int lb_k = tid >> 4;
    const int lb_n = (tid & 15) * 4;

    for (int k0 = 0; k0 < K; k0 += BK) {
#pragma unroll
        for (int half = 0; half < 2; ++half) {
            int r = la_r + half * 64;
            int ar = row0 + r;
            float4 av = make_float4(0.f, 0.f, 0.f, 0.f);
            if (ar < M) av = *(const float4*)(A + (size_t)ar * K + k0 + la_k);
            As[la_k + 0][r] = av.x;
            As[la_k + 1][r] = av.y;
            As[la_k + 2][r] = av.z;
            As[la_k + 3][r] = av.w;
        }
        float4 bv = *(const float4*)(B + (size_t)(k0 + lb_k) * Ncol + col0 + lb_n);
        *(float4*)&Bs[lb_k][lb_n] = bv;
        __syncthreads();

#pragma unroll
        for (int kk = 0; kk < BK; ++kk) {
            float4 a0 = *(const float4*)&As[kk][ty * 8];
            float4 a1 = *(const float4*)&As[kk][ty * 8 + 4];
            float4 b4 = *(const float4*)&Bs[kk][tx * 4];
            float a[8] = {a0.x, a0.y, a0.z, a0.w, a1.x, a1.y, a1.z, a1.w};
            float b[4] = {b4.x, b4.y, b4.z, b4.w};
#pragma unroll
            for (int i = 0; i < 8; ++i)
#pragma unroll
                for (int j = 0; j < 4; ++j) acc[i][j] += a[i] * b[j];
        }
        __syncthreads();
    }
#pragma unroll
    for (int i = 0; i < 8; ++i) {
        int row = row0 + ty * 8 + i;
        if (row < M) {
            float4 v = make_float4(acc[i][0], acc[i][1], acc[i][2], acc[i][3]);
            *(float4*)(C + (size_t)row * Ncol + col0 + tx * 4) = v;
            if (C16) {
                ushort4 u = make_ushort4(f2bf(v.x), f2bf(v.y), f2bf(v.z), f2bf(v.w));
                *(ushort4*)(C16 + (size_t)row * Ncol + col0 + tx * 4) = u;
            }
        }
    }
}

// ---- per-node alpha_src/alpha_dst ----
__global__ __launch_bounds__(256) void node_alpha_kernel(const float* __restrict__ xh,
                                                         const float* __restrict__ a_src,
                                                         const float* __restrict__ a_dst,
                                                         float* __restrict__ asrc,
                                                         float* __restrict__ adst, int N) {
    int n = blockIdx.x;
    int h = threadIdx.x >> 6;
    int c = threadIdx.x & 63;
    float v = xh[(size_t)n * 256 + h * 64 + c];
    float ps = v * a_src[h * 64 + c];
    float pd = v * a_dst[h * 64 + c];
#pragma unroll
    for (int off = 32; off > 0; off >>= 1) {
        ps += __shfl_down(ps, off);
        pd += __shfl_down(pd, off);
    }
    if (c == 0) {
        asrc[n * 4 + h] = ps;
        adst[n * 4 + h] = pd;
    }
}

// ---- ce[h] = sum_c W_e[0, h*64+c] * a_e[h, c] ----
__global__ __launch_bounds__(256) void ce_kernel(const float* __restrict__ W_e,
                                                 const float* __restrict__ a_e,
                                                 float* __restrict__ ce) {
    int h = threadIdx.x >> 6;
    int c = threadIdx.x & 63;
    float p = W_e[h * 64 + c] * a_e[h * 64 + c];
#pragma unroll
    for (int off = 32; off > 0; off >>= 1) p += __shfl_down(p, off);
    if (c == 0) ce[h] = p;
}

// ==================== CSR build ====================
__global__ __launch_bounds__(256) void zero_deg(int* __restrict__ deg, int N) {
    int i = blockIdx.x * blockDim.x + threadIdx.x;
    if (i < N) deg[i] = 0;
}

__global__ __launch_bounds__(256) void hist_kernel(const int* __restrict__ dst,
                                                   int* __restrict__ deg, int E) {
    int e = blockIdx.x * blockDim.x + threadIdx.x;
    if (e < E) atomicAdd(&deg[dst[e]], 1);
}

__global__ __launch_bounds__(1024) void scan_kernel(const int* __restrict__ deg,
                                                    int* __restrict__ off,
                                                    int* __restrict__ cursor, int N) {
    __shared__ int wsum[16];
    __shared__ int woff[16];
    __shared__ int s_carry, s_bt;
    if (threadIdx.x == 0) s_carry = 0;
    __syncthreads();
    const int lane = threadIdx.x & 63, wid = threadIdx.x >> 6;
    for (int base = 0; base < N; base += 1024) {
        int i = base + (int)threadIdx.x;
        int v = (i < N) ? deg[i] : 0;
        int incl = v;
#pragma unroll
        for (int ofs = 1; ofs < 64; ofs <<= 1) {
            int t = __shfl_up(incl, ofs);
            if (lane >= ofs) incl += t;
        }
        if (lane == 63) wsum[wid] = incl;
        __syncthreads();
        if (wid == 0) {
            int ws = (lane < 16) ? wsum[lane] : 0;
            int wincl = ws;
#pragma unroll
            for (int ofs = 1; ofs < 16; ofs <<= 1) {
                int t = __shfl_up(wincl, ofs);
                if (lane >= ofs) wincl += t;
            }
            if (lane < 16) woff[lane] = wincl - ws;
            if (lane == 15) s_bt = wincl;
        }
        __syncthreads();
        int excl = s_carry + woff[wid] + incl - v;
        if (i < N) { off[i] = excl; cursor[i] = excl; }
        __syncthreads();
        if (threadIdx.x == 0) s_carry += s_bt;
        __syncthreads();
    }
    if (threadIdx.x == 0) off[N] = s_carry;
}

__global__ __launch_bounds__(256) void fill_kernel(const int* __restrict__ dst,
                                                   int* __restrict__ cursor,
                                                   int* __restrict__ perm, int E) {
    int e = blockIdx.x * blockDim.x + threadIdx.x;
    if (e < E) {
        int pos = atomicAdd(&cursor[dst[e]], 1);
        perm[pos] = e;
    }
}

// ==================== fused per-node softmax + aggregation ====================
__global__ __launch_bounds__(256) void node_fused(const int* __restrict__ perm,
                                                  const int* __restrict__ off,
                                                  const int* __restrict__ src,
                                                  const float* __restrict__ edge_attr,
                                                  const float* __restrict__ edge_atten,
                                                  const float* __restrict__ asrc,
                                                  const float* __restrict__ adst,
                                                  const float* __restrict__ ce,
                                                  const unsigned short* __restrict__ xh16,
                                                  const float* __restrict__ bias,
                                                  float* __restrict__ w,
                                                  float* __restrict__ hout, int N) {
    __shared__ float s_al[4][CAP * 4];
    __shared__ int s_src[4][CAP];
    const int wid = threadIdx.x >> 6;
    const int n = blockIdx.x * 4 + wid;
    if (n >= N) return;
    const int lane = threadIdx.x & 63;
    float* al = s_al[wid];
    int* sv = s_src[wid];
    const int o0 = off[n], o1 = off[n + 1];
    const int deg = o1 - o0;

    const float4 c4 = *(const float4*)ce;
    const float4 ad4 = *(const float4*)(adst + (size_t)n * 4);

    // phase 1: raw alpha (leakyrelu) per edge, running max
    float4 mx = make_float4(-3.4e38f, -3.4e38f, -3.4e38f, -3.4e38f);
    for (int idx = lane; idx < deg; idx += 64) {
        int e = perm[o0 + idx];
        int s = src[e];
        float ea = edge_attr[e];
        float4 as4 = *(const float4*)(asrc + (size_t)s * 4);
        float4 a;
        a.x = as4.x + ad4.x + ea * c4.x;
        a.y = as4.y + ad4.y + ea * c4.y;
        a.z = as4.z + ad4.z + ea * c4.z;
        a.w = as4.w + ad4.w + ea * c4.w;
        a.x = a.x > 0.f ? a.x : NEG_SLOPE * a.x;
        a.y = a.y > 0.f ? a.y : NEG_SLOPE * a.y;
        a.z = a.z > 0.f ? a.z : NEG_SLOPE * a.z;
        a.w = a.w > 0.f ? a.w : NEG_SLOPE * a.w;
        if (idx < CAP) {
            sv[idx] = s;
            *(float4*)&al[idx * 4] = a;
        } else {
            *(float4*)(w + (size_t)e * 4) = a;  // rare spill
        }
        mx.x = fmaxf(mx.x, a.x);
        mx.y = fmaxf(mx.y, a.y);
        mx.z = fmaxf(mx.z, a.z);
        mx.w = fmaxf(mx.w, a.w);
    }
#pragma unroll
    for (int ofs = 1; ofs < 64; ofs <<= 1) {
        mx.x = fmaxf(mx.x, __shfl_xor(mx.x, ofs));
        mx.y = fmaxf(mx.y, __shfl_xor(mx.y, ofs));
        mx.z = fmaxf(mx.z, __shfl_xor(mx.z, ofs));
        mx.w = fmaxf(mx.w, __shfl_xor(mx.w, ofs));
    }

    // phase 2: exp + sum
    float4 sm = make_float4(0.f, 0.f, 0.f, 0.f);
    for (int idx = lane; idx < deg; idx += 64) {
        float4 a;
        int e = -1;
        if (idx < CAP) a = *(const float4*)&al[idx * 4];
        else { e = perm[o0 + idx]; a = *(const float4*)(w + (size_t)e * 4); }
        a.x = __expf(a.x - mx.x);
        a.y = __expf(a.y - mx.y);
        a.z = __expf(a.z - mx.z);
        a.w = __expf(a.w - mx.w);
        if (idx < CAP) *(float4*)&al[idx * 4] = a;
        else *(float4*)(w + (size_t)e * 4) = a;
        sm.x += a.x; sm.y += a.y; sm.z += a.z; sm.w += a.w;
    }
#pragma unroll
    for (int ofs = 1; ofs < 64; ofs <<= 1) {
        sm.x += __shfl_xor(sm.x, ofs);
        sm.y += __shfl_xor(sm.y, ofs);
        sm.z += __shfl_xor(sm.z, ofs);
        sm.w += __shfl_xor(sm.w, ofs);
    }
    float4 rc;
    rc.x = 1.f / (sm.x + 1e-16f);
    rc.y = 1.f / (sm.y + 1e-16f);
    rc.z = 1.f / (sm.z + 1e-16f);
    rc.w = 1.f / (sm.w + 1e-16f);

    // phase 3: normalize, write w, fold edge_atten into LDS copy
    for (int idx = lane; idx < deg; idx += 64) {
        int e = perm[o0 + idx];
        float4 ex = (idx < CAP) ? *(const float4*)&al[idx * 4]
                                : *(const float4*)(w + (size_t)e * 4);
        float4 aln;
        aln.x = ex.x * rc.x;
        aln.y = ex.y * rc.y;
        aln.z = ex.z * rc.z;
        aln.w = ex.w * rc.w;
        *(float4*)(w + (size_t)e * 4) = aln;
        if (idx < CAP) {
            float att = edge_atten[e];
            aln.x *= att; aln.y *= att; aln.z *= att; aln.w *= att;
            *(float4*)&al[idx * 4] = aln;
        }
    }

    // phase 4: aggregation, lane = channel (4 ch/lane), bf16 gather, unroll x4
    const int hh = lane >> 4;
    float4 acc = *(const float4*)(bias + lane * 4);
    const int kmax = deg < CAP ? deg : CAP;
    int k = 0;
    for (; k + 4 <= kmax; k += 4) {
        int s0 = sv[k], s1 = sv[k + 1], s2 = sv[k + 2], s3 = sv[k + 3];
        float c0 = al[(k + 0) * 4 + hh];
        float c1 = al[(k + 1) * 4 + hh];
        float c2 = al[(k + 2) * 4 + hh];
        float c3 = al[(k + 3) * 4 + hh];
        ushort4 u0 = *((const ushort4*)(xh16 + (size_t)s0 * 256) + lane);
        ushort4 u1 = *((const ushort4*)(xh16 + (size_t)s1 * 256) + lane);
        ushort4 u2 = *((const ushort4*)(xh16 + (size_t)s2 * 256) + lane);
        ushort4 u3 = *((const ushort4*)(xh16 + (size_t)s3 * 256) + lane);
        acc.x += bf2f(u0.x) * c0; acc.y += bf2f(u0.y) * c0; acc.z += bf2f(u0.z) * c0; acc.w += bf2f(u0.w) * c0;
        acc.x += bf2f(u1.x) * c1; acc.y += bf2f(u1.y) * c1; acc.z += bf2f(u1.z) * c1; acc.w += bf2f(u1.w) * c1;
        acc.x += bf2f(u2.x) * c2; acc.y += bf2f(u2.y) * c2; acc.z += bf2f(u2.z) * c2; acc.w += bf2f(u2.w) * c2;
        acc.x += bf2f(u3.x) * c3; acc.y += bf2f(u3.y) * c3; acc.z += bf2f(u3.z) * c3; acc.w += bf2f(u3.w) * c3;
    }
    for (; k < kmax; ++k) {
        int s = sv[k];
        float sc = al[k * 4 + hh];
        ushort4 uv = *((const ushort4*)(xh16 + (size_t)s * 256) + lane);
        acc.x += bf2f(uv.x) * sc; acc.y += bf2f(uv.y) * sc;
        acc.z += bf2f(uv.z) * sc; acc.w += bf2f(uv.w) * sc;
    }
    for (k = CAP; k < deg; ++k) {   // rare spill path
        int e = perm[o0 + k];
        int s = src[e];
        float sc = w[(size_t)e * 4 + hh] * edge_atten[e];
        ushort4 uv = *((const ushort4*)(xh16 + (size_t)s * 256) + lane);
        acc.x += bf2f(uv.x) * sc; acc.y += bf2f(uv.y) * sc;
        acc.z += bf2f(uv.z) * sc; acc.w += bf2f(uv.w) * sc;
    }
    *(float4*)(hout + (size_t)n * 256 + lane * 4) = acc;
}

extern "C" void kernel_launch(void* const* d_in, const int* in_sizes, int n_in,
                              void* d_out, int out_size, void* d_ws, size_t ws_size,
                              hipStream_t stream) {
    const float* x          = (const float*)d_in[0];
    const int*   ei         = (const int*)d_in[1];
    const float* edge_attr  = (const float*)d_in[3];
    const float* edge_atten = (const float*)d_in[4];
    const float* W1     = (const float*)d_in[5];
    const float* a_src1 = (const float*)d_in[6];
    const float* a_dst1 = (const float*)d_in[7];
    const float* W_e1   = (const float*)d_in[8];
    const float* a_e1   = (const float*)d_in[9];
    const float* b1     = (const float*)d_in[10];
    const float* W2     = (const float*)d_in[11];
    const float* a_src2 = (const float*)d_in[12];
    const float* a_dst2 = (const float*)d_in[13];
    const float* W_e2   = (const float*)d_in[14];
    const float* a_e2   = (const float*)d_in[15];
    const float* b2     = (const float*)d_in[16];

    const int N = in_sizes[0] / 128;   // 20000
    const int E = in_sizes[1] / 2;     // 640000
    const int* srcp = ei;
    const int* dstp = ei + E;

    float* ws = (float*)d_ws;
    float* xh   = ws;                                  // N*256
    float* h1   = xh + (size_t)N * 256;                // N*256
    float* asrc = h1 + (size_t)N * 256;                // N*4
    float* adst = asrc + (size_t)N * 4;                // N*4
    float* ce   = adst + (size_t)N * 4;                // 4 (pad 4)
    int* deg    = (int*)(ce + 4);                      // N
    int* off    = deg + N;                             // N+1
    int* cursor = off + N + 1;                         // N
    int* perm   = cursor + N;                          // E
    unsigned short* xh16 = (unsigned short*)(perm + E); // N*256 bf16

    float* hout2 = (float*)d_out;                      // N*256
    float* w1    = hout2 + (size_t)N * 256;            // E*4
    float* w2    = w1 + (size_t)E * 4;                 // E*4

    dim3 gemm_grid(256 / BN, (N + BM - 1) / BM);
    int eb = (E + 255) / 256;
    int nb = (N + 255) / 256;
    int gb = (N + 3) / 4;

    // ---------------- CSR build (once; shared by both layers) ----------------
    zero_deg<<<nb, 256, 0, stream>>>(deg, N);
    hist_kernel<<<eb, 256, 0, stream>>>(dstp, deg, E);
    scan_kernel<<<1, 1024, 0, stream>>>(deg, off, cursor, N);
    fill_kernel<<<eb, 256, 0, stream>>>(dstp, cursor, perm, E);

    // ---------------- layer 1 ----------------
    gemm_kernel<<<gemm_grid, 256, 0, stream>>>(x, W1, xh, xh16, N, 128, 256);
    node_alpha_kernel<<<N, 256, 0, stream>>>(xh, a_src1, a_dst1, asrc, adst, N);
    ce_kernel<<<1, 256, 0, stream>>>(W_e1, a_e1, ce);
    node_fused<<<gb, 256, 0, stream>>>(perm, off, srcp, edge_attr, edge_atten,
                                       asrc, adst, ce, xh16, b1, w1, h1, N);

    // ---------------- layer 2 ----------------
    gemm_kernel<<<gemm_grid, 256, 0, stream>>>(h1, W2, xh, xh16, N, 256, 256);
    node_alpha_kernel<<<N, 256, 0, stream>>>(xh, a_src2, a_dst2, asrc, adst, N);
    ce_kernel<<<1, 256, 0, stream>>>(W_e2, a_e2, ce);
    node_fused<<<gb, 256, 0, stream>>>(perm, off, srcp, edge_attr, edge_atten,
                                       asrc, adst, ce, xh16, b2, w2, hout2, N);
}

// Round 6
// 387.926 us; speedup vs baseline: 12.7580x; 1.1683x over previous
//
#include <hip/hip_runtime.h>
#include <math.h>

#define NEG_SLOPE 0.2f
#define CAP 128   // max in-edges/node in LDS; deg~Binom(640K,1/20K) mean 32 → ample

typedef short s16x8 __attribute__((ext_vector_type(8)));
typedef unsigned short us8 __attribute__((ext_vector_type(8)));
typedef float f32x4 __attribute__((ext_vector_type(4)));

// bf16 helpers (RNE encode, shift decode)
__device__ __forceinline__ unsigned short f2bf(float f) {
    unsigned int u = __float_as_uint(f);
    return (unsigned short)((u + 0x7FFFu + ((u >> 16) & 1u)) >> 16);
}
__device__ __forceinline__ float bf2f(unsigned short s) {
    return __uint_as_float(((unsigned int)s) << 16);
}

// ---- fp32 -> bf16 elementwise ----
__global__ __launch_bounds__(256) void conv_bf16(const float* __restrict__ in,
                                                 unsigned short* __restrict__ out, int n) {
    int i = blockIdx.x * blockDim.x + threadIdx.x;
    if (i < n) out[i] = f2bf(in[i]);
}

// ---- W [K][256] fp32 -> Wt [256][K] bf16 ----
__global__ __launch_bounds__(256) void transpose_w(const float* __restrict__ W,
                                                   unsigned short* __restrict__ Wt,
                                                   int K) {
    int i = blockIdx.x * blockDim.x + threadIdx.x;
    if (i < K * 256) {
        int k = i >> 8, n = i & 255;
        Wt[n * K + k] = f2bf(W[i]);
    }
}

// ---- bf16 MFMA GEMM: C16[M,256] = bf16(A16[M,K] * Bt16^T), Bt16 = B^T [256][K] ----
// block = 256 thr (4 waves); tile 128(M) x 64(N); wave w owns rows [w*32, w*32+32)
__global__ __launch_bounds__(256) void gemm_bf16(const unsigned short* __restrict__ A16,
                                                 const unsigned short* __restrict__ Bt16,
                                                 unsigned short* __restrict__ C16,
                                                 int M, int K) {
    __shared__ unsigned short As[128][40];   // BK=32, pad to 40
    __shared__ unsigned short Bs[64][40];
    const int tid = threadIdx.x;
    const int w = tid >> 6, l = tid & 63;
    const int quad = l >> 4, m16 = l & 15;
    const int row0 = blockIdx.y * 128, col0 = blockIdx.x * 64;

    f32x4 acc[2][4] = {};

    const int a_r = tid >> 1;            // 0..127
    const int a_k = (tid & 1) * 16;      // 0 or 16
    const int b_n = tid >> 2;            // 0..63
    const int b_k = (tid & 3) * 8;       // 0,8,16,24

    for (int k0 = 0; k0 < K; k0 += 32) {
        int gr = row0 + a_r; if (gr > M - 1) gr = M - 1;
        const unsigned short* ap = A16 + (size_t)gr * K + k0 + a_k;
        *(us8*)&As[a_r][a_k]     = *(const us8*)ap;
        *(us8*)&As[a_r][a_k + 8] = *(const us8*)(ap + 8);
        *(us8*)&Bs[b_n][b_k] = *(const us8*)(Bt16 + (size_t)(col0 + b_n) * K + k0 + b_k);
        __syncthreads();

        s16x8 af[2], bf[4];
#pragma unroll
        for (int mt = 0; mt < 2; ++mt)
            af[mt] = *(const s16x8*)&As[w * 32 + mt * 16 + m16][quad * 8];
#pragma unroll
        for (int nt = 0; nt < 4; ++nt)
            bf[nt] = *(const s16x8*)&Bs[nt * 16 + m16][quad * 8];
#pragma unroll
        for (int mt = 0; mt < 2; ++mt)
#pragma unroll
            for (int nt = 0; nt < 4; ++nt)
                acc[mt][nt] = __builtin_amdgcn_mfma_f32_16x16x32_bf16(af[mt], bf[nt], acc[mt][nt], 0, 0, 0);
        __syncthreads();
    }

#pragma unroll
    for (int mt = 0; mt < 2; ++mt)
#pragma unroll
        for (int nt = 0; nt < 4; ++nt) {
            int col = col0 + nt * 16 + m16;
#pragma unroll
            for (int i = 0; i < 4; ++i) {
                int row = row0 + w * 32 + mt * 16 + quad * 4 + i;
                if (row < M) C16[(size_t)row * 256 + col] = f2bf(acc[mt][nt][i]);
            }
        }
}

// ---- per-node alpha_src/alpha_dst (bf16 features) ----
__global__ __launch_bounds__(256) void node_alpha_kernel(const unsigned short* __restrict__ xh16,
                                                         const float* __restrict__ a_src,
                                                         const float* __restrict__ a_dst,
                                                         float* __restrict__ asrc,
                                                         float* __restrict__ adst, int N) {
    int n = blockIdx.x;
    int h = threadIdx.x >> 6;
    int c = threadIdx.x & 63;
    float v = bf2f(xh16[(size_t)n * 256 + h * 64 + c]);
    float ps = v * a_src[h * 64 + c];
    float pd = v * a_dst[h * 64 + c];
#pragma unroll
    for (int off = 32; off > 0; off >>= 1) {
        ps += __shfl_down(ps, off);
        pd += __shfl_down(pd, off);
    }
    if (c == 0) {
        asrc[n * 4 + h] = ps;
        adst[n * 4 + h] = pd;
    }
}

// ---- ce[h] = sum_c W_e[0, h*64+c] * a_e[h, c] ----
__global__ __launch_bounds__(256) void ce_kernel(const float* __restrict__ W_e,
                                                 const float* __restrict__ a_e,
                                                 float* __restrict__ ce) {
    int h = threadIdx.x >> 6;
    int c = threadIdx.x & 63;
    float p = W_e[h * 64 + c] * a_e[h * 64 + c];
#pragma unroll
    for (int off = 32; off > 0; off >>= 1) p += __shfl_down(p, off);
    if (c == 0) ce[h] = p;
}

// ==================== CSR build ====================
__global__ __launch_bounds__(256) void zero_deg(int* __restrict__ deg, int N) {
    int i = blockIdx.x * blockDim.x + threadIdx.x;
    if (i < N) deg[i] = 0;
}

__global__ __launch_bounds__(256) void hist_kernel(const int* __restrict__ dst,
                                                   int* __restrict__ deg, int E) {
    int e = blockIdx.x * blockDim.x + threadIdx.x;
    if (e < E) atomicAdd(&deg[dst[e]], 1);
}

__global__ __launch_bounds__(1024) void scan_kernel(const int* __restrict__ deg,
                                                    int* __restrict__ off,
                                                    int* __restrict__ cursor, int N) {
    __shared__ int wsum[16];
    __shared__ int woff[16];
    __shared__ int s_carry, s_bt;
    if (threadIdx.x == 0) s_carry = 0;
    __syncthreads();
    const int lane = threadIdx.x & 63, wid = threadIdx.x >> 6;
    for (int base = 0; base < N; base += 1024) {
        int i = base + (int)threadIdx.x;
        int v = (i < N) ? deg[i] : 0;
        int incl = v;
#pragma unroll
        for (int ofs = 1; ofs < 64; ofs <<= 1) {
            int t = __shfl_up(incl, ofs);
            if (lane >= ofs) incl += t;
        }
        if (lane == 63) wsum[wid] = incl;
        __syncthreads();
        if (wid == 0) {
            int ws = (lane < 16) ? wsum[lane] : 0;
            int wincl = ws;
#pragma unroll
            for (int ofs = 1; ofs < 16; ofs <<= 1) {
                int t = __shfl_up(wincl, ofs);
                if (lane >= ofs) wincl += t;
            }
            if (lane < 16) woff[lane] = wincl - ws;
            if (lane == 15) s_bt = wincl;
        }
        __syncthreads();
        int excl = s_carry + woff[wid] + incl - v;
        if (i < N) { off[i] = excl; cursor[i] = excl; }
        __syncthreads();
        if (threadIdx.x == 0) s_carry += s_bt;
        __syncthreads();
    }
    if (threadIdx.x == 0) off[N] = s_carry;
}

__global__ __launch_bounds__(256) void fill_kernel(const int* __restrict__ dst,
                                                   int* __restrict__ cursor,
                                                   int* __restrict__ perm, int E) {
    int e = blockIdx.x * blockDim.x + threadIdx.x;
    if (e < E) {
        int pos = atomicAdd(&cursor[dst[e]], 1);
        perm[pos] = e;
    }
}

// ==================== fused per-node softmax + aggregation ====================
__global__ __launch_bounds__(256) void node_fused(const int* __restrict__ perm,
                                                  const int* __restrict__ off,
                                                  const int* __restrict__ src,
                                                  const float* __restrict__ edge_attr,
                                                  const float* __restrict__ edge_atten,
                                                  const float* __restrict__ asrc,
                                                  const float* __restrict__ adst,
                                                  const float* __restrict__ ce,
                                                  const unsigned short* __restrict__ xh16,
                                                  const float* __restrict__ bias,
                                                  float* __restrict__ w,
                                                  float* __restrict__ houtf,        // nullable
                                                  unsigned short* __restrict__ hout16, // nullable
                                                  int N) {
    __shared__ float s_al[4][CAP * 4];
    __shared__ int s_src[4][CAP];
    const int wid = threadIdx.x >> 6;
    const int n = blockIdx.x * 4 + wid;
    if (n >= N) return;
    const int lane = threadIdx.x & 63;
    float* al = s_al[wid];
    int* sv = s_src[wid];
    const int o0 = off[n], o1 = off[n + 1];
    const int deg = o1 - o0;

    const float4 c4 = *(const float4*)ce;
    const float4 ad4 = *(const float4*)(adst + (size_t)n * 4);

    // phase 1: raw alpha (leakyrelu) per edge, running max
    float4 mx = make_float4(-3.4e38f, -3.4e38f, -3.4e38f, -3.4e38f);
    for (int idx = lane; idx < deg; idx += 64) {
        int e = perm[o0 + idx];
        int s = src[e];
        float ea = edge_attr[e];
        float4 as4 = *(const float4*)(asrc + (size_t)s * 4);
        float4 a;
        a.x = as4.x + ad4.x + ea * c4.x;
        a.y = as4.y + ad4.y + ea * c4.y;
        a.z = as4.z + ad4.z + ea * c4.z;
        a.w = as4.w + ad4.w + ea * c4.w;
        a.x = a.x > 0.f ? a.x : NEG_SLOPE * a.x;
        a.y = a.y > 0.f ? a.y : NEG_SLOPE * a.y;
        a.z = a.z > 0.f ? a.z : NEG_SLOPE * a.z;
        a.w = a.w > 0.f ? a.w : NEG_SLOPE * a.w;
        if (idx < CAP) {
            sv[idx] = s;
            *(float4*)&al[idx * 4] = a;
        } else {
            *(float4*)(w + (size_t)e * 4) = a;  // rare spill
        }
        mx.x = fmaxf(mx.x, a.x);
        mx.y = fmaxf(mx.y, a.y);
        mx.z = fmaxf(mx.z, a.z);
        mx.w = fmaxf(mx.w, a.w);
    }
#pragma unroll
    for (int ofs = 1; ofs < 64; ofs <<= 1) {
        mx.x = fmaxf(mx.x, __shfl_xor(mx.x, ofs));
        mx.y = fmaxf(mx.y, __shfl_xor(mx.y, ofs));
        mx.z = fmaxf(mx.z, __shfl_xor(mx.z, ofs));
        mx.w = fmaxf(mx.w, __shfl_xor(mx.w, ofs));
    }

    // phase 2: exp + sum
    float4 sm = make_float4(0.f, 0.f, 0.f, 0.f);
    for (int idx = lane; idx < deg; idx += 64) {
        float4 a;
        int e = -1;
        if (idx < CAP) a = *(const float4*)&al[idx * 4];
        else { e = perm[o0 + idx]; a = *(const float4*)(w + (size_t)e * 4); }
        a.x = __expf(a.x - mx.x);
        a.y = __expf(a.y - mx.y);
        a.z = __expf(a.z - mx.z);
        a.w = __expf(a.w - mx.w);
        if (idx < CAP) *(float4*)&al[idx * 4] = a;
        else *(float4*)(w + (size_t)e * 4) = a;
        sm.x += a.x; sm.y += a.y; sm.z += a.z; sm.w += a.w;
    }
#pragma unroll
    for (int ofs = 1; ofs < 64; ofs <<= 1) {
        sm.x += __shfl_xor(sm.x, ofs);
        sm.y += __shfl_xor(sm.y, ofs);
        sm.z += __shfl_xor(sm.z, ofs);
        sm.w += __shfl_xor(sm.w, ofs);
    }
    float4 rc;
    rc.x = 1.f / (sm.x + 1e-16f);
    rc.y = 1.f / (sm.y + 1e-16f);
    rc.z = 1.f / (sm.z + 1e-16f);
    rc.w = 1.f / (sm.w + 1e-16f);

    // phase 3: normalize, write w, fold edge_atten into LDS copy
    for (int idx = lane; idx < deg; idx += 64) {
        int e = perm[o0 + idx];
        float4 ex = (idx < CAP) ? *(const float4*)&al[idx * 4]
                                : *(const float4*)(w + (size_t)e * 4);
        float4 aln;
        aln.x = ex.x * rc.x;
        aln.y = ex.y * rc.y;
        aln.z = ex.z * rc.z;
        aln.w = ex.w * rc.w;
        *(float4*)(w + (size_t)e * 4) = aln;
        if (idx < CAP) {
            float att = edge_atten[e];
            aln.x *= att; aln.y *= att; aln.z *= att; aln.w *= att;
            *(float4*)&al[idx * 4] = aln;
        }
    }

    // phase 4: aggregation, lane = channel (4 ch/lane), bf16 gather, unroll x4
    const int hh = lane >> 4;
    float4 acc = *(const float4*)(bias + lane * 4);
    const int kmax = deg < CAP ? deg : CAP;
    int k = 0;
    for (; k + 4 <= kmax; k += 4) {
        int s0 = sv[k], s1 = sv[k + 1], s2 = sv[k + 2], s3 = sv[k + 3];
        float c0 = al[(k + 0) * 4 + hh];
        float c1 = al[(k + 1) * 4 + hh];
        float c2 = al[(k + 2) * 4 + hh];
        float c3 = al[(k + 3) * 4 + hh];
        ushort4 u0 = *((const ushort4*)(xh16 + (size_t)s0 * 256) + lane);
        ushort4 u1 = *((const ushort4*)(xh16 + (size_t)s1 * 256) + lane);
        ushort4 u2 = *((const ushort4*)(xh16 + (size_t)s2 * 256) + lane);
        ushort4 u3 = *((const ushort4*)(xh16 + (size_t)s3 * 256) + lane);
        acc.x += bf2f(u0.x) * c0; acc.y += bf2f(u0.y) * c0; acc.z += bf2f(u0.z) * c0; acc.w += bf2f(u0.w) * c0;
        acc.x += bf2f(u1.x) * c1; acc.y += bf2f(u1.y) * c1; acc.z += bf2f(u1.z) * c1; acc.w += bf2f(u1.w) * c1;
        acc.x += bf2f(u2.x) * c2; acc.y += bf2f(u2.y) * c2; acc.z += bf2f(u2.z) * c2; acc.w += bf2f(u2.w) * c2;
        acc.x += bf2f(u3.x) * c3; acc.y += bf2f(u3.y) * c3; acc.z += bf2f(u3.z) * c3; acc.w += bf2f(u3.w) * c3;
    }
    for (; k < kmax; ++k) {
        int s = sv[k];
        float sc = al[k * 4 + hh];
        ushort4 uv = *((const ushort4*)(xh16 + (size_t)s * 256) + lane);
        acc.x += bf2f(uv.x) * sc; acc.y += bf2f(uv.y) * sc;
        acc.z += bf2f(uv.z) * sc; acc.w += bf2f(uv.w) * sc;
    }
    for (k = CAP; k < deg; ++k) {   // rare spill path
        int e = perm[o0 + k];
        int s = src[e];
        float sc = w[(size_t)e * 4 + hh] * edge_atten[e];
        ushort4 uv = *((const ushort4*)(xh16 + (size_t)s * 256) + lane);
        acc.x += bf2f(uv.x) * sc; acc.y += bf2f(uv.y) * sc;
        acc.z += bf2f(uv.z) * sc; acc.w += bf2f(uv.w) * sc;
    }
    if (houtf)  *(float4*)(houtf + (size_t)n * 256 + lane * 4) = acc;
    if (hout16) {
        ushort4 u = make_ushort4(f2bf(acc.x), f2bf(acc.y), f2bf(acc.z), f2bf(acc.w));
        *((ushort4*)(hout16 + (size_t)n * 256) + lane) = u;
    }
}

extern "C" void kernel_launch(void* const* d_in, const int* in_sizes, int n_in,
                              void* d_out, int out_size, void* d_ws, size_t ws_size,
                              hipStream_t stream) {
    const float* x          = (const float*)d_in[0];
    const int*   ei         = (const int*)d_in[1];
    const float* edge_attr  = (const float*)d_in[3];
    const float* edge_atten = (const float*)d_in[4];
    const float* W1     = (const float*)d_in[5];
    const float* a_src1 = (const float*)d_in[6];
    const float* a_dst1 = (const float*)d_in[7];
    const float* W_e1   = (const float*)d_in[8];
    const float* a_e1   = (const float*)d_in[9];
    const float* b1     = (const float*)d_in[10];
    const float* W2     = (const float*)d_in[11];
    const float* a_src2 = (const float*)d_in[12];
    const float* a_dst2 = (const float*)d_in[13];
    const float* W_e2   = (const float*)d_in[14];
    const float* a_e2   = (const float*)d_in[15];
    const float* b2     = (const float*)d_in[16];

    const int N = in_sizes[0] / 128;   // 20000
    const int E = in_sizes[1] / 2;     // 640000
    const int* srcp = ei;
    const int* dstp = ei + E;

    char* ws = (char*)d_ws;
    unsigned short* x16   = (unsigned short*)ws;            ws += (size_t)N * 128 * 2;
    unsigned short* xh16  = (unsigned short*)ws;            ws += (size_t)N * 256 * 2;
    unsigned short* h116  = (unsigned short*)ws;            ws += (size_t)N * 256 * 2;
    unsigned short* Wt1   = (unsigned short*)ws;            ws += (size_t)256 * 128 * 2;
    unsigned short* Wt2   = (unsigned short*)ws;            ws += (size_t)256 * 256 * 2;
    float* asrc = (float*)ws;                               ws += (size_t)N * 4 * 4;
    float* adst = (float*)ws;                               ws += (size_t)N * 4 * 4;
    float* ce   = (float*)ws;                               ws += 16;
    int* deg    = (int*)ws;                                 ws += (size_t)N * 4;
    int* off    = (int*)ws;                                 ws += (size_t)(N + 1) * 4;
    int* cursor = (int*)ws;                                 ws += (size_t)N * 4;
    int* perm   = (int*)ws;                                 ws += (size_t)E * 4;

    float* hout2 = (float*)d_out;                      // N*256
    float* w1    = hout2 + (size_t)N * 256;            // E*4
    float* w2    = w1 + (size_t)E * 4;                 // E*4

    dim3 gemm_grid(4, (N + 127) / 128);
    int eb = (E + 255) / 256;
    int nb = (N + 255) / 256;
    int gb = (N + 3) / 4;

    // ---------------- conversions + CSR build (shared) ----------------
    conv_bf16<<<(N * 128 + 255) / 256, 256, 0, stream>>>(x, x16, N * 128);
    transpose_w<<<(128 * 256 + 255) / 256, 256, 0, stream>>>(W1, Wt1, 128);
    transpose_w<<<(256 * 256 + 255) / 256, 256, 0, stream>>>(W2, Wt2, 256);
    zero_deg<<<nb, 256, 0, stream>>>(deg, N);
    hist_kernel<<<eb, 256, 0, stream>>>(dstp, deg, E);
    scan_kernel<<<1, 1024, 0, stream>>>(deg, off, cursor, N);
    fill_kernel<<<eb, 256, 0, stream>>>(dstp, cursor, perm, E);

    // ---------------- layer 1 ----------------
    gemm_bf16<<<gemm_grid, 256, 0, stream>>>(x16, Wt1, xh16, N, 128);
    node_alpha_kernel<<<N, 256, 0, stream>>>(xh16, a_src1, a_dst1, asrc, adst, N);
    ce_kernel<<<1, 256, 0, stream>>>(W_e1, a_e1, ce);
    node_fused<<<gb, 256, 0, stream>>>(perm, off, srcp, edge_attr, edge_atten,
                                       asrc, adst, ce, xh16, b1, w1,
                                       (float*)nullptr, h116, N);

    // ---------------- layer 2 ----------------
    gemm_bf16<<<gemm_grid, 256, 0, stream>>>(h116, Wt2, xh16, N, 256);
    node_alpha_kernel<<<N, 256, 0, stream>>>(xh16, a_src2, a_dst2, asrc, adst, N);
    ce_kernel<<<1, 256, 0, stream>>>(W_e2, a_e2, ce);
    node_fused<<<gb, 256, 0, stream>>>(perm, off, srcp, edge_attr, edge_atten,
                                       asrc, adst, ce, xh16, b2, w2,
                                       hout2, (unsigned short*)nullptr, N);
}